// Round 7
// baseline (915.577 us; speedup 1.0000x reference)
//
#include <hip/hip_runtime.h>
#include <math.h>

#define HDIM 128

typedef _Float16 f16;
typedef unsigned short u16;
typedef __attribute__((ext_vector_type(4))) _Float16 f16x4;
typedef __attribute__((ext_vector_type(8))) _Float16 f16x8;
typedef __attribute__((ext_vector_type(4))) float f32x4;

// ================= CSR build =================
__global__ __launch_bounds__(256) void degrank_kernel(
    const int* __restrict__ edg, int* __restrict__ cnt,
    u16* __restrict__ rank, int E) {
  int e = blockIdx.x * 256 + threadIdx.x;
  if (e < E) {
    int src = edg[e];
    int dst = edg[E + e];
    rank[e] = (u16)atomicAdd(&cnt[dst * 16 + (src >> 12)], 1);
  }
}

__global__ __launch_bounds__(256) void nodescan_kernel(
    int* __restrict__ cnt, int* __restrict__ deg, int N) {
  int node = blockIdx.x * 256 + threadIdx.x;
  if (node >= N) return;
  int* c = cnt + node * 16;
  int s = 0;
  #pragma unroll
  for (int b = 0; b < 16; ++b) {
    int v = c[b];
    c[b] = s;
    s += v;
  }
  deg[node] = s;
}

__global__ __launch_bounds__(256) void scan_part_kernel(
    const int* __restrict__ deg, int* __restrict__ bsum, int n, int chunk) {
  __shared__ int red[256];
  const int b = blockIdx.x, t = threadIdx.x;
  const int begin = b * chunk;
  const int end = min(begin + chunk, n);
  int s = 0;
  for (int i = begin + t; i < end; i += 256) s += deg[i];
  red[t] = s;
  __syncthreads();
  for (int off = 128; off > 0; off >>= 1) {
    if (t < off) red[t] += red[t + off];
    __syncthreads();
  }
  if (t == 0) bsum[b] = red[0];
}

__global__ __launch_bounds__(256) void scan_top_kernel(
    const int* __restrict__ bsum, int* __restrict__ boff,
    int* __restrict__ offs, int n) {
  __shared__ int sh[256];
  const int t = threadIdx.x;
  int v = bsum[t];
  sh[t] = v;
  __syncthreads();
  for (int off = 1; off < 256; off <<= 1) {
    int add = (t >= off) ? sh[t - off] : 0;
    __syncthreads();
    sh[t] += add;
    __syncthreads();
  }
  boff[t] = sh[t] - v;
  if (t == 255) offs[n] = sh[255];
}

__global__ __launch_bounds__(256) void scan_fin_kernel(
    const int* __restrict__ deg, const int* __restrict__ boff,
    int* __restrict__ offs, int n, int chunk) {
  __shared__ int sh[256];
  const int b = blockIdx.x, t = threadIdx.x;
  const int idx = b * chunk + t;
  int v = (t < chunk && idx < n) ? deg[idx] : 0;
  sh[t] = v;
  __syncthreads();
  for (int off = 1; off < 256; off <<= 1) {
    int add = (t >= off) ? sh[t - off] : 0;
    __syncthreads();
    sh[t] += add;
    __syncthreads();
  }
  if (t < chunk && idx < n) offs[idx] = boff[b] + sh[t] - v;
}

__global__ __launch_bounds__(256) void fill_kernel(
    const int* __restrict__ edg, const int* __restrict__ offs,
    const int* __restrict__ cnt, const u16* __restrict__ rank,
    u16* __restrict__ csr_src, int E) {
  int i = blockIdx.x * 256 + threadIdx.x;
  int e0 = i * 4;
  if (e0 >= E) return;
  if (e0 + 4 <= E) {
    int4 s4 = *reinterpret_cast<const int4*>(edg + e0);
    int4 d4 = *reinterpret_cast<const int4*>(edg + E + e0);
    ushort4 r4 = *reinterpret_cast<const ushort4*>(rank + e0);
    csr_src[offs[d4.x] + cnt[d4.x * 16 + (s4.x >> 12)] + r4.x] = (u16)s4.x;
    csr_src[offs[d4.y] + cnt[d4.y * 16 + (s4.y >> 12)] + r4.y] = (u16)s4.y;
    csr_src[offs[d4.z] + cnt[d4.z * 16 + (s4.z >> 12)] + r4.z] = (u16)s4.z;
    csr_src[offs[d4.w] + cnt[d4.w * 16 + (s4.w >> 12)] + r4.w] = (u16)s4.w;
  } else {
    for (int e = e0; e < E; ++e) {
      int src = edg[e];
      int dst = edg[E + e];
      csr_src[offs[dst] + cnt[dst * 16 + (src >> 12)] + rank[e]] = (u16)src;
    }
  }
}

// ===== degree-sort: counting sort of nodes by degree (descending) =====
// removes intra-wave divergence in the pull kernels (wave = 16 nodes with
// per-node loop bounds; unsorted Poisson(32) degrees waste ~30% lane-cycles)
__global__ __launch_bounds__(256) void hist_kernel(
    const int* __restrict__ deg, int* __restrict__ hist, int N) {
  int node = blockIdx.x * 256 + threadIdx.x;
  if (node < N) atomicAdd(&hist[255 - min(deg[node], 255)], 1);
}

__global__ __launch_bounds__(256) void hscan_kernel(int* __restrict__ hist) {
  __shared__ int sh[256];
  const int t = threadIdx.x;
  int v = hist[t];
  sh[t] = v;
  __syncthreads();
  for (int off = 1; off < 256; off <<= 1) {
    int add = (t >= off) ? sh[t - off] : 0;
    __syncthreads();
    sh[t] += add;
    __syncthreads();
  }
  hist[t] = sh[t] - v;   // exclusive
}

__global__ __launch_bounds__(256) void scatter_kernel(
    const int* __restrict__ deg, int* __restrict__ hoff,
    int* __restrict__ perm, int N) {
  int node = blockIdx.x * 256 + threadIdx.x;
  if (node < N) {
    int pos = atomicAdd(&hoff[255 - min(deg[node], 255)], 1);
    perm[pos] = node;
  }
}

// ===== fp32 [n][128] -> blocked fp16 [4][SN][32] (slice s = cols 32s..32s+31)
__global__ __launch_bounds__(256) void convb_kernel(
    const float* __restrict__ src, f16* __restrict__ dst, int n, int SN) {
  const int t = threadIdx.x;
  const int nloc = t >> 3;
  const int sub = t & 7;
  const int sl = sub >> 1;
  const int hf = sub & 1;
  const int node = blockIdx.x * 32 + nloc;
  if (node >= n) return;
  const float* sp = src + (size_t)node * HDIM + sub * 16;
  f16* dp = dst + ((size_t)sl * SN + node) * 32 + hf * 16;
  float4 v0 = *reinterpret_cast<const float4*>(sp + 0);
  float4 v1 = *reinterpret_cast<const float4*>(sp + 4);
  float4 v2 = *reinterpret_cast<const float4*>(sp + 8);
  float4 v3 = *reinterpret_cast<const float4*>(sp + 12);
  f16x8 o0, o1;
  o0[0]=(f16)v0.x; o0[1]=(f16)v0.y; o0[2]=(f16)v0.z; o0[3]=(f16)v0.w;
  o0[4]=(f16)v1.x; o0[5]=(f16)v1.y; o0[6]=(f16)v1.z; o0[7]=(f16)v1.w;
  o1[0]=(f16)v2.x; o1[1]=(f16)v2.y; o1[2]=(f16)v2.z; o1[3]=(f16)v2.w;
  o1[4]=(f16)v3.x; o1[5]=(f16)v3.y; o1[6]=(f16)v3.z; o1[7]=(f16)v3.w;
  *reinterpret_cast<f16x8*>(dp) = o0;
  *reinterpret_cast<f16x8*>(dp + 8) = o1;
}

// ================= W transpose + fp16: WT[gate][n][k] =================
__global__ __launch_bounds__(256) void transw_kernel(
    const float* __restrict__ W, f16* __restrict__ WT) {
  __shared__ float sh[32][33];
  const int g = blockIdx.y;
  const int ti = blockIdx.x >> 2;
  const int tj = blockIdx.x & 3;
  const float* __restrict__ wp = W + (size_t)g * HDIM * HDIM;
  f16* __restrict__ op = WT + (size_t)g * HDIM * HDIM;
  const int t = threadIdx.x;
  #pragma unroll
  for (int it = 0; it < 4; ++it) {
    int elem = it * 256 + t;
    int r = elem >> 5, c = elem & 31;
    sh[r][c] = wp[(size_t)(ti * 32 + r) * HDIM + tj * 32 + c];
  }
  __syncthreads();
  #pragma unroll
  for (int it = 0; it < 4; ++it) {
    int elem = it * 256 + t;
    int cc = elem >> 5, rr = elem & 31;
    op[(size_t)(tj * 32 + cc) * HDIM + ti * 32 + rr] = (f16)sh[rr][cc];
  }
}

// ================= XCD-sliced, degree-sorted pull aggregation =============
// class = blockIdx&7 = (table = cls>>2, slice = cls&3); round-robin
// blockIdx->XCD => each XCD gathers one 3.2MB table slice (L2-resident).
// node = perm[sorted index] => waves process equal-degree nodes (no
// divergence); descending order packs the scheduling tail.
__global__ __launch_bounds__(256) void pull2_kernel(
    const u16* __restrict__ csr_src, const int* __restrict__ offs,
    const int* __restrict__ perm,
    const f16* __restrict__ xb, const f16* __restrict__ hbl,
    f16* __restrict__ A, f16* __restrict__ Bh, int N, int hSN) {
  const int cls = blockIdx.x & 7;
  const int tid = cls >> 2;            // 0 = x-table, 1 = h-table
  const int sl = cls & 3;
  const int snode = (blockIdx.x >> 3) * 64 + (threadIdx.x >> 2);
  if (snode >= N) return;
  const int node = perm[snode];
  const int c8 = (threadIdx.x & 3) << 3;
  const f16* __restrict__ tab =
      tid ? hbl + (size_t)sl * hSN * 32 : xb + (size_t)sl * (size_t)N * 32;
  f16* __restrict__ dst = (tid ? Bh : A) + (size_t)sl * (size_t)N * 32;
  const int s = offs[node];
  const int e = offs[node + 1];
  float acc[8];
  f16x8 sv = *reinterpret_cast<const f16x8*>(tab + (size_t)node * 32 + c8);
  #pragma unroll
  for (int q = 0; q < 8; ++q) acc[q] = (float)sv[q];
  int k = s;
  for (; k + 8 <= e; k += 8) {
    int j0 = csr_src[k];
    int j1 = csr_src[k + 1];
    int j2 = csr_src[k + 2];
    int j3 = csr_src[k + 3];
    int j4 = csr_src[k + 4];
    int j5 = csr_src[k + 5];
    int j6 = csr_src[k + 6];
    int j7 = csr_src[k + 7];
    f16x8 u0 = *reinterpret_cast<const f16x8*>(tab + (size_t)j0 * 32 + c8);
    f16x8 u1 = *reinterpret_cast<const f16x8*>(tab + (size_t)j1 * 32 + c8);
    f16x8 u2 = *reinterpret_cast<const f16x8*>(tab + (size_t)j2 * 32 + c8);
    f16x8 u3 = *reinterpret_cast<const f16x8*>(tab + (size_t)j3 * 32 + c8);
    f16x8 u4 = *reinterpret_cast<const f16x8*>(tab + (size_t)j4 * 32 + c8);
    f16x8 u5 = *reinterpret_cast<const f16x8*>(tab + (size_t)j5 * 32 + c8);
    f16x8 u6 = *reinterpret_cast<const f16x8*>(tab + (size_t)j6 * 32 + c8);
    f16x8 u7 = *reinterpret_cast<const f16x8*>(tab + (size_t)j7 * 32 + c8);
    #pragma unroll
    for (int q = 0; q < 8; ++q)
      acc[q] += (((float)u0[q] + (float)u1[q]) + ((float)u2[q] + (float)u3[q])) +
                (((float)u4[q] + (float)u5[q]) + ((float)u6[q] + (float)u7[q]));
  }
  for (; k < e; ++k) {
    f16x8 u = *reinterpret_cast<const f16x8*>(tab + (size_t)csr_src[k] * 32 + c8);
    #pragma unroll
    for (int q = 0; q < 8; ++q) acc[q] += (float)u[q];
  }
  f16x8 o;
  #pragma unroll
  for (int q = 0; q < 8; ++q) o[q] = (f16)acc[q];
  *reinterpret_cast<f16x8*>(dst + (size_t)node * 32 + c8) = o;
}

__global__ __launch_bounds__(256) void pull1_kernel(
    const u16* __restrict__ csr_src, const int* __restrict__ offs,
    const int* __restrict__ perm,
    const f16* __restrict__ cb, f16* __restrict__ Ctot, int N) {
  const int sl = blockIdx.x & 3;
  const int snode = (blockIdx.x >> 2) * 64 + (threadIdx.x >> 2);
  if (snode >= N) return;
  const int node = perm[snode];
  const int c8 = (threadIdx.x & 3) << 3;
  const f16* __restrict__ tab = cb + (size_t)sl * (size_t)N * 32;
  f16* __restrict__ dst = Ctot + (size_t)sl * (size_t)N * 32;
  const int s = offs[node];
  const int e = offs[node + 1];
  float acc[8];
  f16x8 sv = *reinterpret_cast<const f16x8*>(tab + (size_t)node * 32 + c8);
  #pragma unroll
  for (int q = 0; q < 8; ++q) acc[q] = (float)sv[q];
  int k = s;
  for (; k + 8 <= e; k += 8) {
    int j0 = csr_src[k];
    int j1 = csr_src[k + 1];
    int j2 = csr_src[k + 2];
    int j3 = csr_src[k + 3];
    int j4 = csr_src[k + 4];
    int j5 = csr_src[k + 5];
    int j6 = csr_src[k + 6];
    int j7 = csr_src[k + 7];
    f16x8 u0 = *reinterpret_cast<const f16x8*>(tab + (size_t)j0 * 32 + c8);
    f16x8 u1 = *reinterpret_cast<const f16x8*>(tab + (size_t)j1 * 32 + c8);
    f16x8 u2 = *reinterpret_cast<const f16x8*>(tab + (size_t)j2 * 32 + c8);
    f16x8 u3 = *reinterpret_cast<const f16x8*>(tab + (size_t)j3 * 32 + c8);
    f16x8 u4 = *reinterpret_cast<const f16x8*>(tab + (size_t)j4 * 32 + c8);
    f16x8 u5 = *reinterpret_cast<const f16x8*>(tab + (size_t)j5 * 32 + c8);
    f16x8 u6 = *reinterpret_cast<const f16x8*>(tab + (size_t)j6 * 32 + c8);
    f16x8 u7 = *reinterpret_cast<const f16x8*>(tab + (size_t)j7 * 32 + c8);
    #pragma unroll
    for (int q = 0; q < 8; ++q)
      acc[q] += (((float)u0[q] + (float)u1[q]) + ((float)u2[q] + (float)u3[q])) +
                (((float)u4[q] + (float)u5[q]) + ((float)u6[q] + (float)u7[q]));
  }
  for (; k < e; ++k) {
    f16x8 u = *reinterpret_cast<const f16x8*>(tab + (size_t)csr_src[k] * 32 + c8);
    #pragma unroll
    for (int q = 0; q < 8; ++q) acc[q] += (float)u[q];
  }
  f16x8 o;
  #pragma unroll
  for (int q = 0; q < 8; ++q) o[q] = (f16)acc[q];
  *reinterpret_cast<f16x8*>(dst + (size_t)node * 32 + c8) = o;
}

// ========== LDS staging from blocked [4][SN][32] layout ==========
__device__ __forceinline__ void stage_blocked(
    const f16* __restrict__ src, f16* __restrict__ As,
    int row0, int N, int SN, int t) {
  #pragma unroll
  for (int i = 0; i < 4; ++i) {
    int u = i * 256 + t;          // 1024 chunks of 16B
    int row = u >> 4;
    int sl = (u >> 2) & 3;
    int ck = u & 3;
    int r = row0 + row;
    f16x8 v{};
    if (r < N) v = *reinterpret_cast<const f16x8*>(
        src + ((size_t)sl * SN + r) * 32 + ck * 8);
    *reinterpret_cast<f16x8*>(&As[row * 136 + sl * 32 + ck * 8]) = v;
  }
}

__device__ __forceinline__ void mfma_tile(
    const f16* As, const f16* Ws, int wr, int wc, int ln15, int quad,
    f32x4 (&acc)[2][4]) {
  #pragma unroll
  for (int s = 0; s < 4; ++s) {
    f16x8 a0 = *reinterpret_cast<const f16x8*>(
        &As[(wr * 32 + ln15) * 136 + s * 32 + quad * 8]);
    f16x8 a1 = *reinterpret_cast<const f16x8*>(
        &As[(wr * 32 + 16 + ln15) * 136 + s * 32 + quad * 8]);
    #pragma unroll
    for (int ni = 0; ni < 4; ++ni) {
      f16x8 bf = *reinterpret_cast<const f16x8*>(
          &Ws[(wc * 64 + ni * 16 + ln15) * 136 + s * 32 + quad * 8]);
      acc[0][ni] = __builtin_amdgcn_mfma_f32_16x16x32_f16(a0, bf, acc[0][ni], 0, 0, 0);
      acc[1][ni] = __builtin_amdgcn_mfma_f32_16x16x32_f16(a1, bf, acc[1][ni], 0, 0, 0);
    }
  }
}

// ============ fused gate GEMM (z, r, h-partial in one pass) ========
__global__ __launch_bounds__(256, 3) void gemm3_kernel(
    const f16* __restrict__ A, const f16* __restrict__ Bh,
    const f16* __restrict__ WT, const float* __restrict__ b,
    const f16* __restrict__ hbl, f16* __restrict__ zb,
    f16* __restrict__ cb, f16* __restrict__ hpre, int N, int hSN) {
  __shared__ f16 As[64 * 136];
  __shared__ f16 Ws[128 * 136];
  const int t = threadIdx.x;
  const int w = t >> 6, wr = w >> 1, wc = w & 1;
  const int lane = t & 63, ln15 = lane & 15, quad = lane >> 4;
  const int row0 = blockIdx.x * 64;
  f32x4 accZ[2][4], accR[2][4], accH[2][4];
  #pragma unroll
  for (int i = 0; i < 2; ++i)
    #pragma unroll
    for (int j = 0; j < 4; ++j) {
      accZ[i][j] = (f32x4){0.f, 0.f, 0.f, 0.f};
      accR[i][j] = (f32x4){0.f, 0.f, 0.f, 0.f};
      accH[i][j] = (f32x4){0.f, 0.f, 0.f, 0.f};
    }

  stage_blocked(A, As, row0, N, N, t);
  #pragma unroll
  for (int g = 0; g < 3; ++g) {          // gates 0,2,4 vs x-aggregate
    const f16* __restrict__ wp = WT + (size_t)(g * 2) * HDIM * HDIM;
    __syncthreads();
    #pragma unroll
    for (int i = 0; i < 8; ++i) {
      int flat = i * 256 + t;
      int n = flat >> 4;
      int o = (flat & 15) * 8;
      *reinterpret_cast<f16x8*>(&Ws[n * 136 + o]) =
          *reinterpret_cast<const f16x8*>(wp + (size_t)n * HDIM + o);
    }
    __syncthreads();
    if (g == 0) mfma_tile(As, Ws, wr, wc, ln15, quad, accZ);
    else if (g == 1) mfma_tile(As, Ws, wr, wc, ln15, quad, accR);
    else mfma_tile(As, Ws, wr, wc, ln15, quad, accH);
  }
  __syncthreads();
  stage_blocked(Bh, As, row0, N, N, t);
  #pragma unroll
  for (int g = 0; g < 2; ++g) {          // gates 1,3 vs h-aggregate
    const f16* __restrict__ wp = WT + (size_t)(g * 2 + 1) * HDIM * HDIM;
    __syncthreads();
    #pragma unroll
    for (int i = 0; i < 8; ++i) {
      int flat = i * 256 + t;
      int n = flat >> 4;
      int o = (flat & 15) * 8;
      *reinterpret_cast<f16x8*>(&Ws[n * 136 + o]) =
          *reinterpret_cast<const f16x8*>(wp + (size_t)n * HDIM + o);
    }
    __syncthreads();
    if (g == 0) mfma_tile(As, Ws, wr, wc, ln15, quad, accZ);
    else mfma_tile(As, Ws, wr, wc, ln15, quad, accR);
  }

  // ---- epilogue: zpre (linear f16), c=sigmoid(r)*h (blocked), hpre (f16) ----
  #pragma unroll
  for (int ni = 0; ni < 4; ++ni) {
    const int col = wc * 64 + ni * 16 + ln15;
    const int slc = col >> 5;
    const int cw = col & 31;
    float bz = b[0 * HDIM + col] + b[1 * HDIM + col];
    float br = b[2 * HDIM + col] + b[3 * HDIM + col];
    float bh = b[4 * HDIM + col];
    #pragma unroll
    for (int mi = 0; mi < 2; ++mi) {
      #pragma unroll
      for (int r = 0; r < 4; ++r) {
        int row = row0 + wr * 32 + mi * 16 + quad * 4 + r;
        if (row >= N) continue;
        size_t idx = (size_t)row * HDIM + col;
        zb[idx] = (f16)(accZ[mi][ni][r] + bz);
        float rv = accR[mi][ni][r] + br;
        float rg = 1.f / (1.f + expf(-rv));
        float hv = (float)hbl[((size_t)slc * hSN + row) * 32 + cw];
        cb[((size_t)slc * N + row) * 32 + cw] = (f16)(rg * hv);
        hpre[idx] = (f16)(accH[mi][ni][r] + bh);
      }
    }
  }
}

// ============ final GEMM + GRU combine =======================
__global__ __launch_bounds__(256, 3) void gemm_final_kernel(
    const f16* __restrict__ Ctot, const f16* __restrict__ WT5,
    const float* __restrict__ b5, const f16* __restrict__ zb,
    const f16* __restrict__ hbl, const f16* __restrict__ hpre,
    float* __restrict__ outi, f16* __restrict__ xb, int N, int hSN) {
  __shared__ f16 As[64 * 136];
  __shared__ f16 Ws[128 * 136];
  const int t = threadIdx.x;
  const int w = t >> 6, wr = w >> 1, wc = w & 1;
  const int lane = t & 63, ln15 = lane & 15, quad = lane >> 4;
  const int row0 = blockIdx.x * 64;
  f32x4 acc[2][4];
  #pragma unroll
  for (int i = 0; i < 2; ++i)
    #pragma unroll
    for (int j = 0; j < 4; ++j) acc[i][j] = (f32x4){0.f, 0.f, 0.f, 0.f};

  stage_blocked(Ctot, As, row0, N, N, t);
  #pragma unroll
  for (int i = 0; i < 8; ++i) {
    int flat = i * 256 + t;
    int n = flat >> 4;
    int o = (flat & 15) * 8;
    *reinterpret_cast<f16x8*>(&Ws[n * 136 + o]) =
        *reinterpret_cast<const f16x8*>(WT5 + (size_t)n * HDIM + o);
  }
  __syncthreads();
  mfma_tile(As, Ws, wr, wc, ln15, quad, acc);

  #pragma unroll
  for (int ni = 0; ni < 4; ++ni) {
    const int col = wc * 64 + ni * 16 + ln15;
    const int slc = col >> 5;
    const int cw = col & 31;
    float bias = b5[col];
    #pragma unroll
    for (int mi = 0; mi < 2; ++mi) {
      #pragma unroll
      for (int r = 0; r < 4; ++r) {
        int row = row0 + wr * 32 + mi * 16 + quad * 4 + r;
        if (row >= N) continue;
        size_t idx = (size_t)row * HDIM + col;
        float v = acc[mi][ni][r] + bias + (float)hpre[idx];
        float ht = tanhf(v);
        float z = 1.f / (1.f + expf(-(float)zb[idx]));
        float hv = (float)hbl[((size_t)slc * hSN + row) * 32 + cw];
        float o = z * hv + (1.f - z) * ht;
        outi[idx] = o;
        xb[((size_t)slc * N + row) * 32 + cw] = (f16)o;  // blocked x table
      }
    }
  }
}

extern "C" void kernel_launch(void* const* d_in, const int* in_sizes, int n_in,
                              void* d_out, int out_size, void* d_ws, size_t ws_size,
                              hipStream_t stream) {
  const float* inp = (const float*)d_in[0];
  const int*   edg = (const int*)d_in[1];
  const float* h   = (const float*)d_in[2];
  const float* W   = (const float*)d_in[3];
  const float* b   = (const float*)d_in[4];
  float* out = (float*)d_out;

  const int NH = in_sizes[0];      // N*H
  const int N  = NH / HDIM;
  const int E  = in_sizes[1] / 2;
  const int L  = in_sizes[2] / NH;

  f16* Af   = (f16*)d_ws;               // x-agg / c-agg (blocked, reused)
  f16* Bhf  = Af + (size_t)NH;          // h-agg (blocked)
  f16* zbuf = Bhf + (size_t)NH;         // zpre (linear)
  f16* cbuf = zbuf + (size_t)NH;        // sigmoid(r)*h (blocked gather table)
  f16* xbuf = cbuf + (size_t)NH;        // x f16 (blocked gather table)
  f16* hpbuf = xbuf + (size_t)NH;       // hpre f16 (linear)
  f16* hbuf = hpbuf + (size_t)NH;       // h f16 both layers (blocked)
  f16* WT   = hbuf + (size_t)L * NH;    // L*6*H*H transposed f16 weights
  int* deg     = (int*)(WT + (size_t)L * 6 * HDIM * HDIM);
  int* offs    = deg + N;               // N+1
  int* bsum    = offs + (N + 1);        // 256
  int* boff    = bsum + 256;            // 256
  int* hist    = boff + 256;            // 256
  int* perm    = hist + 256;            // N
  u16* rank    = (u16*)(perm + N);      // E
  u16* csr_src = rank + (size_t)E;      // E
  // bucket counters: N*16 ints, live only during CSR build -> overlay on Af
  int* cnt     = (int*)Af;

  const int eblocks = (E + 255) / 256;
  const int fblocks = (E + 1023) / 1024;
  const int nsblocks = (N + 255) / 256;
  const int rowblocks = (N + 63) / 64;
  const int p2blocks = ((N + 63) / 64) * 8;
  const int p1blocks = ((N + 63) / 64) * 4;
  const int cvxblocks = (N + 31) / 32;
  const int cvhblocks = (L * N + 31) / 32;
  const int chunk = (N + 255) / 256;    // <=256 requires N<=65536

  // ---- one-time per call: CSR build, degree sort, transpose, f16 tables ----
  hipMemsetAsync(cnt, 0, (size_t)N * 16 * sizeof(int), stream);
  hipMemsetAsync(hist, 0, 256 * sizeof(int), stream);
  hipLaunchKernelGGL(degrank_kernel, dim3(eblocks), dim3(256), 0, stream,
                     edg, cnt, rank, E);
  hipLaunchKernelGGL(nodescan_kernel, dim3(nsblocks), dim3(256), 0, stream,
                     cnt, deg, N);
  hipLaunchKernelGGL(scan_part_kernel, dim3(256), dim3(256), 0, stream,
                     deg, bsum, N, chunk);
  hipLaunchKernelGGL(scan_top_kernel, dim3(1), dim3(256), 0, stream,
                     bsum, boff, offs, N);
  hipLaunchKernelGGL(scan_fin_kernel, dim3(256), dim3(256), 0, stream,
                     deg, boff, offs, N, chunk);
  hipLaunchKernelGGL(fill_kernel, dim3(fblocks), dim3(256), 0, stream,
                     edg, offs, cnt, rank, csr_src, E);
  hipLaunchKernelGGL(hist_kernel, dim3(nsblocks), dim3(256), 0, stream,
                     deg, hist, N);
  hipLaunchKernelGGL(hscan_kernel, dim3(1), dim3(256), 0, stream, hist);
  hipLaunchKernelGGL(scatter_kernel, dim3(nsblocks), dim3(256), 0, stream,
                     deg, hist, perm, N);
  hipLaunchKernelGGL(transw_kernel, dim3(16, L * 6), dim3(256), 0, stream,
                     W, WT);
  hipLaunchKernelGGL(convb_kernel, dim3(cvxblocks), dim3(256), 0, stream,
                     inp, xbuf, N, N);
  hipLaunchKernelGGL(convb_kernel, dim3(cvhblocks), dim3(256), 0, stream,
                     h, hbuf, L * N, L * N);

  for (int i = 0; i < L; ++i) {
    const f16* hbl = hbuf + (size_t)i * N * 32;  // layer-i base (blocked)
    const f16* WTi = WT + (size_t)i * 6 * HDIM * HDIM;
    const float* bi = b + (size_t)i * 6 * HDIM;
    float* outi = out + (size_t)i * NH;

    hipLaunchKernelGGL(pull2_kernel, dim3(p2blocks), dim3(256), 0, stream,
                       csr_src, offs, perm, xbuf, hbl, Af, Bhf, N, L * N);
    hipLaunchKernelGGL(gemm3_kernel, dim3(rowblocks), dim3(256), 0, stream,
                       Af, Bhf, WTi, bi, hbl, zbuf, cbuf, hpbuf, N, L * N);
    hipLaunchKernelGGL(pull1_kernel, dim3(p1blocks), dim3(256), 0, stream,
                       csr_src, offs, perm, cbuf, Af, N);  // Af = c-agg
    hipLaunchKernelGGL(gemm_final_kernel, dim3(rowblocks), dim3(256), 0, stream,
                       Af, WTi + (size_t)5 * HDIM * HDIM, bi + 5 * HDIM,
                       zbuf, hbl, hpbuf, outi, xbuf, N, L * N);
  }
}

// Round 8
// 669.301 us; speedup vs baseline: 1.3680x; 1.3680x over previous
//
#include <hip/hip_runtime.h>
#include <math.h>

#define HDIM 128

typedef _Float16 f16;
typedef unsigned short u16;
typedef __attribute__((ext_vector_type(4))) _Float16 f16x4;
typedef __attribute__((ext_vector_type(8))) _Float16 f16x8;
typedef __attribute__((ext_vector_type(4))) float f32x4;

// ================= CSR build =================
__global__ __launch_bounds__(256) void degrank_kernel(
    const int* __restrict__ edg, int* __restrict__ cnt,
    u16* __restrict__ rank, int E) {
  int e = blockIdx.x * 256 + threadIdx.x;
  if (e < E) {
    int src = edg[e];
    int dst = edg[E + e];
    rank[e] = (u16)atomicAdd(&cnt[dst * 16 + (src >> 12)], 1);
  }
}

__global__ __launch_bounds__(256) void nodescan_kernel(
    int* __restrict__ cnt, int* __restrict__ deg, int N) {
  int node = blockIdx.x * 256 + threadIdx.x;
  if (node >= N) return;
  int* c = cnt + node * 16;
  int s = 0;
  #pragma unroll
  for (int b = 0; b < 16; ++b) {
    int v = c[b];
    c[b] = s;
    s += v;
  }
  deg[node] = s;
}

__global__ __launch_bounds__(256) void scan_part_kernel(
    const int* __restrict__ deg, int* __restrict__ bsum, int n, int chunk) {
  __shared__ int red[256];
  const int b = blockIdx.x, t = threadIdx.x;
  const int begin = b * chunk;
  const int end = min(begin + chunk, n);
  int s = 0;
  for (int i = begin + t; i < end; i += 256) s += deg[i];
  red[t] = s;
  __syncthreads();
  for (int off = 128; off > 0; off >>= 1) {
    if (t < off) red[t] += red[t + off];
    __syncthreads();
  }
  if (t == 0) bsum[b] = red[0];
}

__global__ __launch_bounds__(256) void scan_top_kernel(
    const int* __restrict__ bsum, int* __restrict__ boff,
    int* __restrict__ offs, int n) {
  __shared__ int sh[256];
  const int t = threadIdx.x;
  int v = bsum[t];
  sh[t] = v;
  __syncthreads();
  for (int off = 1; off < 256; off <<= 1) {
    int add = (t >= off) ? sh[t - off] : 0;
    __syncthreads();
    sh[t] += add;
    __syncthreads();
  }
  boff[t] = sh[t] - v;
  if (t == 255) offs[n] = sh[255];
}

__global__ __launch_bounds__(256) void scan_fin_kernel(
    const int* __restrict__ deg, const int* __restrict__ boff,
    int* __restrict__ offs, int n, int chunk) {
  __shared__ int sh[256];
  const int b = blockIdx.x, t = threadIdx.x;
  const int idx = b * chunk + t;
  int v = (t < chunk && idx < n) ? deg[idx] : 0;
  sh[t] = v;
  __syncthreads();
  for (int off = 1; off < 256; off <<= 1) {
    int add = (t >= off) ? sh[t - off] : 0;
    __syncthreads();
    sh[t] += add;
    __syncthreads();
  }
  if (t < chunk && idx < n) offs[idx] = boff[b] + sh[t] - v;
}

__global__ __launch_bounds__(256) void fill_kernel(
    const int* __restrict__ edg, const int* __restrict__ offs,
    const int* __restrict__ cnt, const u16* __restrict__ rank,
    u16* __restrict__ csr_src, int E) {
  int i = blockIdx.x * 256 + threadIdx.x;
  int e0 = i * 4;
  if (e0 >= E) return;
  if (e0 + 4 <= E) {
    int4 s4 = *reinterpret_cast<const int4*>(edg + e0);
    int4 d4 = *reinterpret_cast<const int4*>(edg + E + e0);
    ushort4 r4 = *reinterpret_cast<const ushort4*>(rank + e0);
    csr_src[offs[d4.x] + cnt[d4.x * 16 + (s4.x >> 12)] + r4.x] = (u16)s4.x;
    csr_src[offs[d4.y] + cnt[d4.y * 16 + (s4.y >> 12)] + r4.y] = (u16)s4.y;
    csr_src[offs[d4.z] + cnt[d4.z * 16 + (s4.z >> 12)] + r4.z] = (u16)s4.z;
    csr_src[offs[d4.w] + cnt[d4.w * 16 + (s4.w >> 12)] + r4.w] = (u16)s4.w;
  } else {
    for (int e = e0; e < E; ++e) {
      int src = edg[e];
      int dst = edg[E + e];
      csr_src[offs[dst] + cnt[dst * 16 + (src >> 12)] + rank[e]] = (u16)src;
    }
  }
}

// ===== fp32 [n][128] -> blocked fp16 [4][SN][32] (slice s = cols 32s..32s+31)
__global__ __launch_bounds__(256) void convb_kernel(
    const float* __restrict__ src, f16* __restrict__ dst, int n, int SN) {
  const int t = threadIdx.x;
  const int nloc = t >> 3;
  const int sub = t & 7;
  const int sl = sub >> 1;
  const int hf = sub & 1;
  const int node = blockIdx.x * 32 + nloc;
  if (node >= n) return;
  const float* sp = src + (size_t)node * HDIM + sub * 16;
  f16* dp = dst + ((size_t)sl * SN + node) * 32 + hf * 16;
  float4 v0 = *reinterpret_cast<const float4*>(sp + 0);
  float4 v1 = *reinterpret_cast<const float4*>(sp + 4);
  float4 v2 = *reinterpret_cast<const float4*>(sp + 8);
  float4 v3 = *reinterpret_cast<const float4*>(sp + 12);
  f16x8 o0, o1;
  o0[0]=(f16)v0.x; o0[1]=(f16)v0.y; o0[2]=(f16)v0.z; o0[3]=(f16)v0.w;
  o0[4]=(f16)v1.x; o0[5]=(f16)v1.y; o0[6]=(f16)v1.z; o0[7]=(f16)v1.w;
  o1[0]=(f16)v2.x; o1[1]=(f16)v2.y; o1[2]=(f16)v2.z; o1[3]=(f16)v2.w;
  o1[4]=(f16)v3.x; o1[5]=(f16)v3.y; o1[6]=(f16)v3.z; o1[7]=(f16)v3.w;
  *reinterpret_cast<f16x8*>(dp) = o0;
  *reinterpret_cast<f16x8*>(dp + 8) = o1;
}

// ================= W transpose + fp16: WT[gate][n][k] =================
__global__ __launch_bounds__(256) void transw_kernel(
    const float* __restrict__ W, f16* __restrict__ WT) {
  __shared__ float sh[32][33];
  const int g = blockIdx.y;
  const int ti = blockIdx.x >> 2;
  const int tj = blockIdx.x & 3;
  const float* __restrict__ wp = W + (size_t)g * HDIM * HDIM;
  f16* __restrict__ op = WT + (size_t)g * HDIM * HDIM;
  const int t = threadIdx.x;
  #pragma unroll
  for (int it = 0; it < 4; ++it) {
    int elem = it * 256 + t;
    int r = elem >> 5, c = elem & 31;
    sh[r][c] = wp[(size_t)(ti * 32 + r) * HDIM + tj * 32 + c];
  }
  __syncthreads();
  #pragma unroll
  for (int it = 0; it < 4; ++it) {
    int elem = it * 256 + t;
    int cc = elem >> 5, rr = elem & 31;
    op[(size_t)(tj * 32 + cc) * HDIM + ti * 32 + rr] = (f16)sh[rr][cc];
  }
}

// ================= XCD-sliced pull aggregation =================
// class = blockIdx&7 = (table = cls>>2, slice = cls&3); round-robin
// blockIdx->XCD => each XCD gathers one 3.2MB table slice (L2-resident).
// Node-slice row = 32 f16 = 64B = one full line; 4 lanes x f16x8 per node.
// Accumulation: groups of 4 edges summed as f16 pair-trees (v_pk_add_f16,
// 2.3x fewer VALU ops), then converted+added into f32 accumulators.
__global__ __launch_bounds__(256) void pull2_kernel(
    const u16* __restrict__ csr_src, const int* __restrict__ offs,
    const f16* __restrict__ xb, const f16* __restrict__ hbl,
    f16* __restrict__ A, f16* __restrict__ Bh, int N, int hSN) {
  const int cls = blockIdx.x & 7;
  const int tid = cls >> 2;            // 0 = x-table, 1 = h-table
  const int sl = cls & 3;
  const int node = (blockIdx.x >> 3) * 64 + (threadIdx.x >> 2);
  if (node >= N) return;
  const int c8 = (threadIdx.x & 3) << 3;
  const f16* __restrict__ tab =
      tid ? hbl + (size_t)sl * hSN * 32 : xb + (size_t)sl * (size_t)N * 32;
  f16* __restrict__ dst = (tid ? Bh : A) + (size_t)sl * (size_t)N * 32;
  const int s = offs[node];
  const int e = offs[node + 1];
  float acc[8];
  f16x8 sv = *reinterpret_cast<const f16x8*>(tab + (size_t)node * 32 + c8);
  #pragma unroll
  for (int q = 0; q < 8; ++q) acc[q] = (float)sv[q];
  int k = s;
  for (; k + 16 <= e; k += 16) {
    int j0 = csr_src[k];      int j1 = csr_src[k + 1];
    int j2 = csr_src[k + 2];  int j3 = csr_src[k + 3];
    int j4 = csr_src[k + 4];  int j5 = csr_src[k + 5];
    int j6 = csr_src[k + 6];  int j7 = csr_src[k + 7];
    int j8 = csr_src[k + 8];  int j9 = csr_src[k + 9];
    int ja = csr_src[k + 10]; int jb = csr_src[k + 11];
    int jc = csr_src[k + 12]; int jd = csr_src[k + 13];
    int je = csr_src[k + 14]; int jf = csr_src[k + 15];
    f16x8 u0 = *reinterpret_cast<const f16x8*>(tab + (size_t)j0 * 32 + c8);
    f16x8 u1 = *reinterpret_cast<const f16x8*>(tab + (size_t)j1 * 32 + c8);
    f16x8 u2 = *reinterpret_cast<const f16x8*>(tab + (size_t)j2 * 32 + c8);
    f16x8 u3 = *reinterpret_cast<const f16x8*>(tab + (size_t)j3 * 32 + c8);
    f16x8 u4 = *reinterpret_cast<const f16x8*>(tab + (size_t)j4 * 32 + c8);
    f16x8 u5 = *reinterpret_cast<const f16x8*>(tab + (size_t)j5 * 32 + c8);
    f16x8 u6 = *reinterpret_cast<const f16x8*>(tab + (size_t)j6 * 32 + c8);
    f16x8 u7 = *reinterpret_cast<const f16x8*>(tab + (size_t)j7 * 32 + c8);
    f16x8 u8 = *reinterpret_cast<const f16x8*>(tab + (size_t)j8 * 32 + c8);
    f16x8 u9 = *reinterpret_cast<const f16x8*>(tab + (size_t)j9 * 32 + c8);
    f16x8 ua = *reinterpret_cast<const f16x8*>(tab + (size_t)ja * 32 + c8);
    f16x8 ub = *reinterpret_cast<const f16x8*>(tab + (size_t)jb * 32 + c8);
    f16x8 uc = *reinterpret_cast<const f16x8*>(tab + (size_t)jc * 32 + c8);
    f16x8 ud = *reinterpret_cast<const f16x8*>(tab + (size_t)jd * 32 + c8);
    f16x8 ue = *reinterpret_cast<const f16x8*>(tab + (size_t)je * 32 + c8);
    f16x8 uf = *reinterpret_cast<const f16x8*>(tab + (size_t)jf * 32 + c8);
    f16x8 g0 = (u0 + u1) + (u2 + u3);   // f16 pair-tree (v_pk_add_f16)
    f16x8 g1 = (u4 + u5) + (u6 + u7);
    f16x8 g2 = (u8 + u9) + (ua + ub);
    f16x8 g3 = (uc + ud) + (ue + uf);
    #pragma unroll
    for (int q = 0; q < 8; ++q)
      acc[q] += ((float)g0[q] + (float)g1[q]) + ((float)g2[q] + (float)g3[q]);
  }
  for (; k + 4 <= e; k += 4) {
    int j0 = csr_src[k];     int j1 = csr_src[k + 1];
    int j2 = csr_src[k + 2]; int j3 = csr_src[k + 3];
    f16x8 u0 = *reinterpret_cast<const f16x8*>(tab + (size_t)j0 * 32 + c8);
    f16x8 u1 = *reinterpret_cast<const f16x8*>(tab + (size_t)j1 * 32 + c8);
    f16x8 u2 = *reinterpret_cast<const f16x8*>(tab + (size_t)j2 * 32 + c8);
    f16x8 u3 = *reinterpret_cast<const f16x8*>(tab + (size_t)j3 * 32 + c8);
    f16x8 g = (u0 + u1) + (u2 + u3);
    #pragma unroll
    for (int q = 0; q < 8; ++q) acc[q] += (float)g[q];
  }
  for (; k < e; ++k) {
    f16x8 u = *reinterpret_cast<const f16x8*>(tab + (size_t)csr_src[k] * 32 + c8);
    #pragma unroll
    for (int q = 0; q < 8; ++q) acc[q] += (float)u[q];
  }
  f16x8 o;
  #pragma unroll
  for (int q = 0; q < 8; ++q) o[q] = (f16)acc[q];
  *reinterpret_cast<f16x8*>(dst + (size_t)node * 32 + c8) = o;
}

// single-table sliced pull: class = blockIdx&3 (slice); 64 nodes x 4 lanes
__global__ __launch_bounds__(256) void pull1_kernel(
    const u16* __restrict__ csr_src, const int* __restrict__ offs,
    const f16* __restrict__ cb, f16* __restrict__ Ctot, int N) {
  const int sl = blockIdx.x & 3;
  const int node = (blockIdx.x >> 2) * 64 + (threadIdx.x >> 2);
  if (node >= N) return;
  const int c8 = (threadIdx.x & 3) << 3;
  const f16* __restrict__ tab = cb + (size_t)sl * (size_t)N * 32;
  f16* __restrict__ dst = Ctot + (size_t)sl * (size_t)N * 32;
  const int s = offs[node];
  const int e = offs[node + 1];
  float acc[8];
  f16x8 sv = *reinterpret_cast<const f16x8*>(tab + (size_t)node * 32 + c8);
  #pragma unroll
  for (int q = 0; q < 8; ++q) acc[q] = (float)sv[q];
  int k = s;
  for (; k + 16 <= e; k += 16) {
    int j0 = csr_src[k];      int j1 = csr_src[k + 1];
    int j2 = csr_src[k + 2];  int j3 = csr_src[k + 3];
    int j4 = csr_src[k + 4];  int j5 = csr_src[k + 5];
    int j6 = csr_src[k + 6];  int j7 = csr_src[k + 7];
    int j8 = csr_src[k + 8];  int j9 = csr_src[k + 9];
    int ja = csr_src[k + 10]; int jb = csr_src[k + 11];
    int jc = csr_src[k + 12]; int jd = csr_src[k + 13];
    int je = csr_src[k + 14]; int jf = csr_src[k + 15];
    f16x8 u0 = *reinterpret_cast<const f16x8*>(tab + (size_t)j0 * 32 + c8);
    f16x8 u1 = *reinterpret_cast<const f16x8*>(tab + (size_t)j1 * 32 + c8);
    f16x8 u2 = *reinterpret_cast<const f16x8*>(tab + (size_t)j2 * 32 + c8);
    f16x8 u3 = *reinterpret_cast<const f16x8*>(tab + (size_t)j3 * 32 + c8);
    f16x8 u4 = *reinterpret_cast<const f16x8*>(tab + (size_t)j4 * 32 + c8);
    f16x8 u5 = *reinterpret_cast<const f16x8*>(tab + (size_t)j5 * 32 + c8);
    f16x8 u6 = *reinterpret_cast<const f16x8*>(tab + (size_t)j6 * 32 + c8);
    f16x8 u7 = *reinterpret_cast<const f16x8*>(tab + (size_t)j7 * 32 + c8);
    f16x8 u8 = *reinterpret_cast<const f16x8*>(tab + (size_t)j8 * 32 + c8);
    f16x8 u9 = *reinterpret_cast<const f16x8*>(tab + (size_t)j9 * 32 + c8);
    f16x8 ua = *reinterpret_cast<const f16x8*>(tab + (size_t)ja * 32 + c8);
    f16x8 ub = *reinterpret_cast<const f16x8*>(tab + (size_t)jb * 32 + c8);
    f16x8 uc = *reinterpret_cast<const f16x8*>(tab + (size_t)jc * 32 + c8);
    f16x8 ud = *reinterpret_cast<const f16x8*>(tab + (size_t)jd * 32 + c8);
    f16x8 ue = *reinterpret_cast<const f16x8*>(tab + (size_t)je * 32 + c8);
    f16x8 uf = *reinterpret_cast<const f16x8*>(tab + (size_t)jf * 32 + c8);
    f16x8 g0 = (u0 + u1) + (u2 + u3);
    f16x8 g1 = (u4 + u5) + (u6 + u7);
    f16x8 g2 = (u8 + u9) + (ua + ub);
    f16x8 g3 = (uc + ud) + (ue + uf);
    #pragma unroll
    for (int q = 0; q < 8; ++q)
      acc[q] += ((float)g0[q] + (float)g1[q]) + ((float)g2[q] + (float)g3[q]);
  }
  for (; k + 4 <= e; k += 4) {
    int j0 = csr_src[k];     int j1 = csr_src[k + 1];
    int j2 = csr_src[k + 2]; int j3 = csr_src[k + 3];
    f16x8 u0 = *reinterpret_cast<const f16x8*>(tab + (size_t)j0 * 32 + c8);
    f16x8 u1 = *reinterpret_cast<const f16x8*>(tab + (size_t)j1 * 32 + c8);
    f16x8 u2 = *reinterpret_cast<const f16x8*>(tab + (size_t)j2 * 32 + c8);
    f16x8 u3 = *reinterpret_cast<const f16x8*>(tab + (size_t)j3 * 32 + c8);
    f16x8 g = (u0 + u1) + (u2 + u3);
    #pragma unroll
    for (int q = 0; q < 8; ++q) acc[q] += (float)g[q];
  }
  for (; k < e; ++k) {
    f16x8 u = *reinterpret_cast<const f16x8*>(tab + (size_t)csr_src[k] * 32 + c8);
    #pragma unroll
    for (int q = 0; q < 8; ++q) acc[q] += (float)u[q];
  }
  f16x8 o;
  #pragma unroll
  for (int q = 0; q < 8; ++q) o[q] = (f16)acc[q];
  *reinterpret_cast<f16x8*>(dst + (size_t)node * 32 + c8) = o;
}

// ========== LDS staging from blocked [4][SN][32] layout ==========
__device__ __forceinline__ void stage_blocked(
    const f16* __restrict__ src, f16* __restrict__ As,
    int row0, int N, int SN, int t) {
  #pragma unroll
  for (int i = 0; i < 4; ++i) {
    int u = i * 256 + t;          // 1024 chunks of 16B
    int row = u >> 4;
    int sl = (u >> 2) & 3;
    int ck = u & 3;
    int r = row0 + row;
    f16x8 v{};
    if (r < N) v = *reinterpret_cast<const f16x8*>(
        src + ((size_t)sl * SN + r) * 32 + ck * 8);
    *reinterpret_cast<f16x8*>(&As[row * 136 + sl * 32 + ck * 8]) = v;
  }
}

__device__ __forceinline__ void mfma_tile(
    const f16* As, const f16* Ws, int wr, int wc, int ln15, int quad,
    f32x4 (&acc)[2][4]) {
  #pragma unroll
  for (int s = 0; s < 4; ++s) {
    f16x8 a0 = *reinterpret_cast<const f16x8*>(
        &As[(wr * 32 + ln15) * 136 + s * 32 + quad * 8]);
    f16x8 a1 = *reinterpret_cast<const f16x8*>(
        &As[(wr * 32 + 16 + ln15) * 136 + s * 32 + quad * 8]);
    #pragma unroll
    for (int ni = 0; ni < 4; ++ni) {
      f16x8 bf = *reinterpret_cast<const f16x8*>(
          &Ws[(wc * 64 + ni * 16 + ln15) * 136 + s * 32 + quad * 8]);
      acc[0][ni] = __builtin_amdgcn_mfma_f32_16x16x32_f16(a0, bf, acc[0][ni], 0, 0, 0);
      acc[1][ni] = __builtin_amdgcn_mfma_f32_16x16x32_f16(a1, bf, acc[1][ni], 0, 0, 0);
    }
  }
}

// ============ fused gate GEMM (z, r, h-partial in one pass) ========
__global__ __launch_bounds__(256, 3) void gemm3_kernel(
    const f16* __restrict__ A, const f16* __restrict__ Bh,
    const f16* __restrict__ WT, const float* __restrict__ b,
    const f16* __restrict__ hbl, f16* __restrict__ zb,
    f16* __restrict__ cb, float* __restrict__ hpre, int N, int hSN) {
  __shared__ f16 As[64 * 136];
  __shared__ f16 Ws[128 * 136];
  const int t = threadIdx.x;
  const int w = t >> 6, wr = w >> 1, wc = w & 1;
  const int lane = t & 63, ln15 = lane & 15, quad = lane >> 4;
  const int row0 = blockIdx.x * 64;
  f32x4 accZ[2][4], accR[2][4], accH[2][4];
  #pragma unroll
  for (int i = 0; i < 2; ++i)
    #pragma unroll
    for (int j = 0; j < 4; ++j) {
      accZ[i][j] = (f32x4){0.f, 0.f, 0.f, 0.f};
      accR[i][j] = (f32x4){0.f, 0.f, 0.f, 0.f};
      accH[i][j] = (f32x4){0.f, 0.f, 0.f, 0.f};
    }

  stage_blocked(A, As, row0, N, N, t);
  #pragma unroll
  for (int g = 0; g < 3; ++g) {          // gates 0,2,4 vs x-aggregate
    const f16* __restrict__ wp = WT + (size_t)(g * 2) * HDIM * HDIM;
    __syncthreads();
    #pragma unroll
    for (int i = 0; i < 8; ++i) {
      int flat = i * 256 + t;
      int n = flat >> 4;
      int o = (flat & 15) * 8;
      *reinterpret_cast<f16x8*>(&Ws[n * 136 + o]) =
          *reinterpret_cast<const f16x8*>(wp + (size_t)n * HDIM + o);
    }
    __syncthreads();
    if (g == 0) mfma_tile(As, Ws, wr, wc, ln15, quad, accZ);
    else if (g == 1) mfma_tile(As, Ws, wr, wc, ln15, quad, accR);
    else mfma_tile(As, Ws, wr, wc, ln15, quad, accH);
  }
  __syncthreads();
  stage_blocked(Bh, As, row0, N, N, t);
  #pragma unroll
  for (int g = 0; g < 2; ++g) {          // gates 1,3 vs h-aggregate
    const f16* __restrict__ wp = WT + (size_t)(g * 2 + 1) * HDIM * HDIM;
    __syncthreads();
    #pragma unroll
    for (int i = 0; i < 8; ++i) {
      int flat = i * 256 + t;
      int n = flat >> 4;
      int o = (flat & 15) * 8;
      *reinterpret_cast<f16x8*>(&Ws[n * 136 + o]) =
          *reinterpret_cast<const f16x8*>(wp + (size_t)n * HDIM + o);
    }
    __syncthreads();
    if (g == 0) mfma_tile(As, Ws, wr, wc, ln15, quad, accZ);
    else mfma_tile(As, Ws, wr, wc, ln15, quad, accR);
  }

  // ---- epilogue: zpre (linear), c=sigmoid(r)*h (blocked), hpre (f32) ----
  #pragma unroll
  for (int ni = 0; ni < 4; ++ni) {
    const int col = wc * 64 + ni * 16 + ln15;
    const int slc = col >> 5;
    const int cw = col & 31;
    float bz = b[0 * HDIM + col] + b[1 * HDIM + col];
    float br = b[2 * HDIM + col] + b[3 * HDIM + col];
    float bh = b[4 * HDIM + col];
    #pragma unroll
    for (int mi = 0; mi < 2; ++mi) {
      #pragma unroll
      for (int r = 0; r < 4; ++r) {
        int row = row0 + wr * 32 + mi * 16 + quad * 4 + r;
        if (row >= N) continue;
        size_t idx = (size_t)row * HDIM + col;
        zb[idx] = (f16)(accZ[mi][ni][r] + bz);
        float rv = accR[mi][ni][r] + br;
        float rg = 1.f / (1.f + expf(-rv));
        float hv = (float)hbl[((size_t)slc * hSN + row) * 32 + cw];
        cb[((size_t)slc * N + row) * 32 + cw] = (f16)(rg * hv);
        hpre[idx] = accH[mi][ni][r] + bh;
      }
    }
  }
}

// ============ final GEMM + GRU combine =======================
__global__ __launch_bounds__(256, 3) void gemm_final_kernel(
    const f16* __restrict__ Ctot, const f16* __restrict__ WT5,
    const float* __restrict__ b5, const f16* __restrict__ zb,
    const f16* __restrict__ hbl, float* __restrict__ outi,
    f16* __restrict__ xb, int N, int hSN) {
  __shared__ f16 As[64 * 136];
  __shared__ f16 Ws[128 * 136];
  const int t = threadIdx.x;
  const int w = t >> 6, wr = w >> 1, wc = w & 1;
  const int lane = t & 63, ln15 = lane & 15, quad = lane >> 4;
  const int row0 = blockIdx.x * 64;
  f32x4 acc[2][4];
  #pragma unroll
  for (int i = 0; i < 2; ++i)
    #pragma unroll
    for (int j = 0; j < 4; ++j) acc[i][j] = (f32x4){0.f, 0.f, 0.f, 0.f};

  stage_blocked(Ctot, As, row0, N, N, t);
  #pragma unroll
  for (int i = 0; i < 8; ++i) {
    int flat = i * 256 + t;
    int n = flat >> 4;
    int o = (flat & 15) * 8;
    *reinterpret_cast<f16x8*>(&Ws[n * 136 + o]) =
        *reinterpret_cast<const f16x8*>(WT5 + (size_t)n * HDIM + o);
  }
  __syncthreads();
  mfma_tile(As, Ws, wr, wc, ln15, quad, acc);

  #pragma unroll
  for (int ni = 0; ni < 4; ++ni) {
    const int col = wc * 64 + ni * 16 + ln15;
    const int slc = col >> 5;
    const int cw = col & 31;
    float bias = b5[col];
    #pragma unroll
    for (int mi = 0; mi < 2; ++mi) {
      #pragma unroll
      for (int r = 0; r < 4; ++r) {
        int row = row0 + wr * 32 + mi * 16 + quad * 4 + r;
        if (row >= N) continue;
        size_t idx = (size_t)row * HDIM + col;
        float v = acc[mi][ni][r] + bias + outi[idx];  // + hpre (f32 in outi)
        float ht = tanhf(v);
        float z = 1.f / (1.f + expf(-(float)zb[idx]));
        float hv = (float)hbl[((size_t)slc * hSN + row) * 32 + cw];
        float o = z * hv + (1.f - z) * ht;
        outi[idx] = o;
        xb[((size_t)slc * N + row) * 32 + cw] = (f16)o;  // blocked x table
      }
    }
  }
}

extern "C" void kernel_launch(void* const* d_in, const int* in_sizes, int n_in,
                              void* d_out, int out_size, void* d_ws, size_t ws_size,
                              hipStream_t stream) {
  const float* inp = (const float*)d_in[0];
  const int*   edg = (const int*)d_in[1];
  const float* h   = (const float*)d_in[2];
  const float* W   = (const float*)d_in[3];
  const float* b   = (const float*)d_in[4];
  float* out = (float*)d_out;

  const int NH = in_sizes[0];      // N*H
  const int N  = NH / HDIM;
  const int E  = in_sizes[1] / 2;
  const int L  = in_sizes[2] / NH;

  f16* Af   = (f16*)d_ws;               // x-agg / c-agg (blocked, reused)
  f16* Bhf  = Af + (size_t)NH;          // h-agg (blocked)
  f16* zbuf = Bhf + (size_t)NH;         // zpre (linear)
  f16* cbuf = zbuf + (size_t)NH;        // sigmoid(r)*h (blocked gather table)
  f16* xbuf = cbuf + (size_t)NH;        // x f16 (blocked gather table)
  f16* hbuf = xbuf + (size_t)NH;        // h f16 both layers (blocked)
  f16* WT   = hbuf + (size_t)L * NH;    // L*6*H*H transposed f16 weights
  int* deg     = (int*)(WT + (size_t)L * 6 * HDIM * HDIM);
  int* offs    = deg + N;               // N+1
  int* bsum    = offs + (N + 1);        // 256
  int* boff    = bsum + 256;            // 256
  u16* rank    = (u16*)(boff + 256);    // E
  u16* csr_src = rank + (size_t)E;      // E
  // bucket counters: N*16 ints, live only during CSR build -> overlay on Af
  int* cnt     = (int*)Af;

  const int eblocks = (E + 255) / 256;
  const int fblocks = (E + 1023) / 1024;
  const int nsblocks = (N + 255) / 256;
  const int rowblocks = (N + 63) / 64;
  const int p2blocks = ((N + 63) / 64) * 8;
  const int p1blocks = ((N + 63) / 64) * 4;
  const int cvxblocks = (N + 31) / 32;
  const int cvhblocks = (L * N + 31) / 32;
  const int chunk = (N + 255) / 256;    // <=256 requires N<=65536

  // ---- one-time per call: CSR build, transpose, blocked f16 tables ----
  hipMemsetAsync(cnt, 0, (size_t)N * 16 * sizeof(int), stream);
  hipLaunchKernelGGL(degrank_kernel, dim3(eblocks), dim3(256), 0, stream,
                     edg, cnt, rank, E);
  hipLaunchKernelGGL(nodescan_kernel, dim3(nsblocks), dim3(256), 0, stream,
                     cnt, deg, N);
  hipLaunchKernelGGL(scan_part_kernel, dim3(256), dim3(256), 0, stream,
                     deg, bsum, N, chunk);
  hipLaunchKernelGGL(scan_top_kernel, dim3(1), dim3(256), 0, stream,
                     bsum, boff, offs, N);
  hipLaunchKernelGGL(scan_fin_kernel, dim3(256), dim3(256), 0, stream,
                     deg, boff, offs, N, chunk);
  hipLaunchKernelGGL(fill_kernel, dim3(fblocks), dim3(256), 0, stream,
                     edg, offs, cnt, rank, csr_src, E);
  hipLaunchKernelGGL(transw_kernel, dim3(16, L * 6), dim3(256), 0, stream,
                     W, WT);
  hipLaunchKernelGGL(convb_kernel, dim3(cvxblocks), dim3(256), 0, stream,
                     inp, xbuf, N, N);
  hipLaunchKernelGGL(convb_kernel, dim3(cvhblocks), dim3(256), 0, stream,
                     h, hbuf, L * N, L * N);

  for (int i = 0; i < L; ++i) {
    const f16* hbl = hbuf + (size_t)i * N * 32;  // layer-i base (blocked)
    const f16* WTi = WT + (size_t)i * 6 * HDIM * HDIM;
    const float* bi = b + (size_t)i * 6 * HDIM;
    float* outi = out + (size_t)i * NH;

    hipLaunchKernelGGL(pull2_kernel, dim3(p2blocks), dim3(256), 0, stream,
                       csr_src, offs, xbuf, hbl, Af, Bhf, N, L * N);
    hipLaunchKernelGGL(gemm3_kernel, dim3(rowblocks), dim3(256), 0, stream,
                       Af, Bhf, WTi, bi, hbl, zbuf, cbuf, outi, N, L * N);
    hipLaunchKernelGGL(pull1_kernel, dim3(p1blocks), dim3(256), 0, stream,
                       csr_src, offs, cbuf, Af, N);   // Af reused as c-agg
    hipLaunchKernelGGL(gemm_final_kernel, dim3(rowblocks), dim3(256), 0, stream,
                       Af, WTi + (size_t)5 * HDIM * HDIM, bi + 5 * HDIM,
                       zbuf, hbl, outi, xbuf, N, L * N);
  }
}

// Round 9
// 667.244 us; speedup vs baseline: 1.3722x; 1.0031x over previous
//
#include <hip/hip_runtime.h>
#include <math.h>
#include <stdint.h>

#define HDIM 128

typedef _Float16 f16;
typedef unsigned short u16;
typedef __attribute__((ext_vector_type(8))) unsigned short u16x8;
typedef __attribute__((ext_vector_type(4))) _Float16 f16x4;
typedef __attribute__((ext_vector_type(8))) _Float16 f16x8;
typedef __attribute__((ext_vector_type(4))) float f32x4;

// ================= CSR build =================
__global__ __launch_bounds__(256) void degrank_kernel(
    const int* __restrict__ edg, int* __restrict__ cnt,
    u16* __restrict__ rank, int E) {
  int e = blockIdx.x * 256 + threadIdx.x;
  if (e < E) {
    int src = edg[e];
    int dst = edg[E + e];
    rank[e] = (u16)atomicAdd(&cnt[dst * 16 + (src >> 12)], 1);
  }
}

// exclusive-scan 16 bucket counters; emit true degree and 8-padded degree
__global__ __launch_bounds__(256) void nodescan_kernel(
    int* __restrict__ cnt, int* __restrict__ deg, int* __restrict__ degt,
    int N) {
  int node = blockIdx.x * 256 + threadIdx.x;
  if (node >= N) return;
  int* c = cnt + node * 16;
  int s = 0;
  #pragma unroll
  for (int b = 0; b < 16; ++b) {
    int v = c[b];
    c[b] = s;
    s += v;
  }
  degt[node] = s;
  deg[node] = (s + 7) & ~7;     // pad to multiple of 8
}

__global__ __launch_bounds__(256) void scan_part_kernel(
    const int* __restrict__ deg, int* __restrict__ bsum, int n, int chunk) {
  __shared__ int red[256];
  const int b = blockIdx.x, t = threadIdx.x;
  const int begin = b * chunk;
  const int end = min(begin + chunk, n);
  int s = 0;
  for (int i = begin + t; i < end; i += 256) s += deg[i];
  red[t] = s;
  __syncthreads();
  for (int off = 128; off > 0; off >>= 1) {
    if (t < off) red[t] += red[t + off];
    __syncthreads();
  }
  if (t == 0) bsum[b] = red[0];
}

__global__ __launch_bounds__(256) void scan_top_kernel(
    const int* __restrict__ bsum, int* __restrict__ boff,
    int* __restrict__ offs, int n) {
  __shared__ int sh[256];
  const int t = threadIdx.x;
  int v = bsum[t];
  sh[t] = v;
  __syncthreads();
  for (int off = 1; off < 256; off <<= 1) {
    int add = (t >= off) ? sh[t - off] : 0;
    __syncthreads();
    sh[t] += add;
    __syncthreads();
  }
  boff[t] = sh[t] - v;
  if (t == 255) offs[n] = sh[255];
}

__global__ __launch_bounds__(256) void scan_fin_kernel(
    const int* __restrict__ deg, const int* __restrict__ boff,
    int* __restrict__ offs, int n, int chunk) {
  __shared__ int sh[256];
  const int b = blockIdx.x, t = threadIdx.x;
  const int idx = b * chunk + t;
  int v = (t < chunk && idx < n) ? deg[idx] : 0;
  sh[t] = v;
  __syncthreads();
  for (int off = 1; off < 256; off <<= 1) {
    int add = (t >= off) ? sh[t - off] : 0;
    __syncthreads();
    sh[t] += add;
    __syncthreads();
  }
  if (t < chunk && idx < n) offs[idx] = boff[b] + sh[t] - v;
}

__global__ __launch_bounds__(256) void fill_kernel(
    const int* __restrict__ edg, const int* __restrict__ offs,
    const int* __restrict__ cnt, const u16* __restrict__ rank,
    u16* __restrict__ csr_src, int E) {
  int i = blockIdx.x * 256 + threadIdx.x;
  int e0 = i * 4;
  if (e0 >= E) return;
  if (e0 + 4 <= E) {
    int4 s4 = *reinterpret_cast<const int4*>(edg + e0);
    int4 d4 = *reinterpret_cast<const int4*>(edg + E + e0);
    ushort4 r4 = *reinterpret_cast<const ushort4*>(rank + e0);
    csr_src[offs[d4.x] + cnt[d4.x * 16 + (s4.x >> 12)] + r4.x] = (u16)s4.x;
    csr_src[offs[d4.y] + cnt[d4.y * 16 + (s4.y >> 12)] + r4.y] = (u16)s4.y;
    csr_src[offs[d4.z] + cnt[d4.z * 16 + (s4.z >> 12)] + r4.z] = (u16)s4.z;
    csr_src[offs[d4.w] + cnt[d4.w * 16 + (s4.w >> 12)] + r4.w] = (u16)s4.w;
  } else {
    for (int e = e0; e < E; ++e) {
      int src = edg[e];
      int dst = edg[E + e];
      csr_src[offs[dst] + cnt[dst * 16 + (src >> 12)] + rank[e]] = (u16)src;
    }
  }
}

// fill pad slots [offs+degt, offs+deg) with zero-row index N
__global__ __launch_bounds__(256) void pad_kernel(
    const int* __restrict__ offs, const int* __restrict__ degt,
    const int* __restrict__ deg, u16* __restrict__ csr, int N) {
  int n = blockIdx.x * 256 + threadIdx.x;
  if (n >= N) return;
  int base = offs[n];
  int a = degt[n], b = deg[n];
  for (int k = base + a; k < base + b; ++k) csr[k] = (u16)N;
}

// zero the pad rows (row N per slice) of x, c and per-layer h tables
__global__ __launch_bounds__(256) void zpad_kernel(
    f16* __restrict__ xb, f16* __restrict__ cb, f16* __restrict__ hb,
    int N, int L) {
  int t = threadIdx.x;
  int rows = 2 + L;
  int total = 4 * rows * 4;
  if (t >= total) return;
  int chunk = t & 3;
  int r = (t >> 2) % rows;
  int sl = (t >> 2) / rows;
  size_t SN1 = (size_t)(N + 1);
  f16* p;
  if (r == 0)      p = xb + (sl * SN1 + N) * 32;
  else if (r == 1) p = cb + (sl * SN1 + N) * 32;
  else {
    int i = r - 2;
    p = hb + ((size_t)sl * L * SN1 + (size_t)i * SN1 + N) * 32;
  }
  f16x8 z{};
  *reinterpret_cast<f16x8*>(p + chunk * 8) = z;
}

// ===== fp32 [n][128] -> blocked fp16 [4][SN][32] with row offset =====
__global__ __launch_bounds__(256) void convb_kernel(
    const float* __restrict__ src, f16* __restrict__ dst, int n, int SN,
    int rowoff) {
  const int t = threadIdx.x;
  const int nloc = t >> 3;
  const int sub = t & 7;
  const int sl = sub >> 1;
  const int hf = sub & 1;
  const int node = blockIdx.x * 32 + nloc;
  if (node >= n) return;
  const float* sp = src + (size_t)node * HDIM + sub * 16;
  f16* dp = dst + ((size_t)sl * SN + rowoff + node) * 32 + hf * 16;
  float4 v0 = *reinterpret_cast<const float4*>(sp + 0);
  float4 v1 = *reinterpret_cast<const float4*>(sp + 4);
  float4 v2 = *reinterpret_cast<const float4*>(sp + 8);
  float4 v3 = *reinterpret_cast<const float4*>(sp + 12);
  f16x8 o0, o1;
  o0[0]=(f16)v0.x; o0[1]=(f16)v0.y; o0[2]=(f16)v0.z; o0[3]=(f16)v0.w;
  o0[4]=(f16)v1.x; o0[5]=(f16)v1.y; o0[6]=(f16)v1.z; o0[7]=(f16)v1.w;
  o1[0]=(f16)v2.x; o1[1]=(f16)v2.y; o1[2]=(f16)v2.z; o1[3]=(f16)v2.w;
  o1[4]=(f16)v3.x; o1[5]=(f16)v3.y; o1[6]=(f16)v3.z; o1[7]=(f16)v3.w;
  *reinterpret_cast<f16x8*>(dp) = o0;
  *reinterpret_cast<f16x8*>(dp + 8) = o1;
}

// ================= W transpose + fp16: WT[gate][n][k] =================
__global__ __launch_bounds__(256) void transw_kernel(
    const float* __restrict__ W, f16* __restrict__ WT) {
  __shared__ float sh[32][33];
  const int g = blockIdx.y;
  const int ti = blockIdx.x >> 2;
  const int tj = blockIdx.x & 3;
  const float* __restrict__ wp = W + (size_t)g * HDIM * HDIM;
  f16* __restrict__ op = WT + (size_t)g * HDIM * HDIM;
  const int t = threadIdx.x;
  #pragma unroll
  for (int it = 0; it < 4; ++it) {
    int elem = it * 256 + t;
    int r = elem >> 5, c = elem & 31;
    sh[r][c] = wp[(size_t)(ti * 32 + r) * HDIM + tj * 32 + c];
  }
  __syncthreads();
  #pragma unroll
  for (int it = 0; it < 4; ++it) {
    int elem = it * 256 + t;
    int cc = elem >> 5, rr = elem & 31;
    op[(size_t)(tj * 32 + cc) * HDIM + ti * 32 + rr] = (f16)sh[rr][cc];
  }
}

// ================= XCD-sliced pull aggregation =================
// class = blockIdx&7 = (table, slice); round-robin blockIdx->XCD keeps one
// 3.2MB table slice L2-resident per XCD. Row = 64B line. CSR segments are
// padded to x8 with zero-row index => vector ushort8 index loads (1 VMEM
// per 8 edges instead of 8) and no scalar tail.
__global__ __launch_bounds__(256) void pull2_kernel(
    const u16* __restrict__ csr_src, const int* __restrict__ offs,
    const f16* __restrict__ xb, const f16* __restrict__ hbl,
    f16* __restrict__ A, f16* __restrict__ Bh, int N, int N1, int hSN) {
  const int cls = blockIdx.x & 7;
  const int tid = cls >> 2;            // 0 = x-table, 1 = h-table
  const int sl = cls & 3;
  const int node = (blockIdx.x >> 3) * 64 + (threadIdx.x >> 2);
  if (node >= N) return;
  const int c8 = (threadIdx.x & 3) << 3;
  const f16* __restrict__ tab =
      tid ? hbl + (size_t)sl * hSN * 32 : xb + (size_t)sl * (size_t)N1 * 32;
  f16* __restrict__ dst = (tid ? Bh : A) + (size_t)sl * (size_t)N1 * 32;
  const int s = offs[node];
  const int e = offs[node + 1];
  float acc[8];
  f16x8 sv = *reinterpret_cast<const f16x8*>(tab + (size_t)node * 32 + c8);
  #pragma unroll
  for (int q = 0; q < 8; ++q) acc[q] = (float)sv[q];
  int k = s;
  for (; k + 16 <= e; k += 16) {
    u16x8 ia = *reinterpret_cast<const u16x8*>(csr_src + k);
    u16x8 ib = *reinterpret_cast<const u16x8*>(csr_src + k + 8);
    f16x8 u0 = *reinterpret_cast<const f16x8*>(tab + (size_t)ia[0] * 32 + c8);
    f16x8 u1 = *reinterpret_cast<const f16x8*>(tab + (size_t)ia[1] * 32 + c8);
    f16x8 u2 = *reinterpret_cast<const f16x8*>(tab + (size_t)ia[2] * 32 + c8);
    f16x8 u3 = *reinterpret_cast<const f16x8*>(tab + (size_t)ia[3] * 32 + c8);
    f16x8 u4 = *reinterpret_cast<const f16x8*>(tab + (size_t)ia[4] * 32 + c8);
    f16x8 u5 = *reinterpret_cast<const f16x8*>(tab + (size_t)ia[5] * 32 + c8);
    f16x8 u6 = *reinterpret_cast<const f16x8*>(tab + (size_t)ia[6] * 32 + c8);
    f16x8 u7 = *reinterpret_cast<const f16x8*>(tab + (size_t)ia[7] * 32 + c8);
    f16x8 u8 = *reinterpret_cast<const f16x8*>(tab + (size_t)ib[0] * 32 + c8);
    f16x8 u9 = *reinterpret_cast<const f16x8*>(tab + (size_t)ib[1] * 32 + c8);
    f16x8 ua = *reinterpret_cast<const f16x8*>(tab + (size_t)ib[2] * 32 + c8);
    f16x8 ub = *reinterpret_cast<const f16x8*>(tab + (size_t)ib[3] * 32 + c8);
    f16x8 uc = *reinterpret_cast<const f16x8*>(tab + (size_t)ib[4] * 32 + c8);
    f16x8 ud = *reinterpret_cast<const f16x8*>(tab + (size_t)ib[5] * 32 + c8);
    f16x8 ue = *reinterpret_cast<const f16x8*>(tab + (size_t)ib[6] * 32 + c8);
    f16x8 uf = *reinterpret_cast<const f16x8*>(tab + (size_t)ib[7] * 32 + c8);
    f16x8 g0 = (u0 + u1) + (u2 + u3);   // f16 pair-tree (v_pk_add_f16)
    f16x8 g1 = (u4 + u5) + (u6 + u7);
    f16x8 g2 = (u8 + u9) + (ua + ub);
    f16x8 g3 = (uc + ud) + (ue + uf);
    #pragma unroll
    for (int q = 0; q < 8; ++q)
      acc[q] += ((float)g0[q] + (float)g1[q]) + ((float)g2[q] + (float)g3[q]);
  }
  if (k < e) {                           // exactly 8 remain (padded)
    u16x8 ia = *reinterpret_cast<const u16x8*>(csr_src + k);
    f16x8 u0 = *reinterpret_cast<const f16x8*>(tab + (size_t)ia[0] * 32 + c8);
    f16x8 u1 = *reinterpret_cast<const f16x8*>(tab + (size_t)ia[1] * 32 + c8);
    f16x8 u2 = *reinterpret_cast<const f16x8*>(tab + (size_t)ia[2] * 32 + c8);
    f16x8 u3 = *reinterpret_cast<const f16x8*>(tab + (size_t)ia[3] * 32 + c8);
    f16x8 u4 = *reinterpret_cast<const f16x8*>(tab + (size_t)ia[4] * 32 + c8);
    f16x8 u5 = *reinterpret_cast<const f16x8*>(tab + (size_t)ia[5] * 32 + c8);
    f16x8 u6 = *reinterpret_cast<const f16x8*>(tab + (size_t)ia[6] * 32 + c8);
    f16x8 u7 = *reinterpret_cast<const f16x8*>(tab + (size_t)ia[7] * 32 + c8);
    f16x8 g0 = (u0 + u1) + (u2 + u3);
    f16x8 g1 = (u4 + u5) + (u6 + u7);
    #pragma unroll
    for (int q = 0; q < 8; ++q) acc[q] += (float)g0[q] + (float)g1[q];
  }
  f16x8 o;
  #pragma unroll
  for (int q = 0; q < 8; ++q) o[q] = (f16)acc[q];
  *reinterpret_cast<f16x8*>(dst + (size_t)node * 32 + c8) = o;
}

__global__ __launch_bounds__(256) void pull1_kernel(
    const u16* __restrict__ csr_src, const int* __restrict__ offs,
    const f16* __restrict__ cb, f16* __restrict__ Ctot, int N, int N1) {
  const int sl = blockIdx.x & 3;
  const int node = (blockIdx.x >> 2) * 64 + (threadIdx.x >> 2);
  if (node >= N) return;
  const int c8 = (threadIdx.x & 3) << 3;
  const f16* __restrict__ tab = cb + (size_t)sl * (size_t)N1 * 32;
  f16* __restrict__ dst = Ctot + (size_t)sl * (size_t)N1 * 32;
  const int s = offs[node];
  const int e = offs[node + 1];
  float acc[8];
  f16x8 sv = *reinterpret_cast<const f16x8*>(tab + (size_t)node * 32 + c8);
  #pragma unroll
  for (int q = 0; q < 8; ++q) acc[q] = (float)sv[q];
  int k = s;
  for (; k + 16 <= e; k += 16) {
    u16x8 ia = *reinterpret_cast<const u16x8*>(csr_src + k);
    u16x8 ib = *reinterpret_cast<const u16x8*>(csr_src + k + 8);
    f16x8 u0 = *reinterpret_cast<const f16x8*>(tab + (size_t)ia[0] * 32 + c8);
    f16x8 u1 = *reinterpret_cast<const f16x8*>(tab + (size_t)ia[1] * 32 + c8);
    f16x8 u2 = *reinterpret_cast<const f16x8*>(tab + (size_t)ia[2] * 32 + c8);
    f16x8 u3 = *reinterpret_cast<const f16x8*>(tab + (size_t)ia[3] * 32 + c8);
    f16x8 u4 = *reinterpret_cast<const f16x8*>(tab + (size_t)ia[4] * 32 + c8);
    f16x8 u5 = *reinterpret_cast<const f16x8*>(tab + (size_t)ia[5] * 32 + c8);
    f16x8 u6 = *reinterpret_cast<const f16x8*>(tab + (size_t)ia[6] * 32 + c8);
    f16x8 u7 = *reinterpret_cast<const f16x8*>(tab + (size_t)ia[7] * 32 + c8);
    f16x8 u8 = *reinterpret_cast<const f16x8*>(tab + (size_t)ib[0] * 32 + c8);
    f16x8 u9 = *reinterpret_cast<const f16x8*>(tab + (size_t)ib[1] * 32 + c8);
    f16x8 ua = *reinterpret_cast<const f16x8*>(tab + (size_t)ib[2] * 32 + c8);
    f16x8 ub = *reinterpret_cast<const f16x8*>(tab + (size_t)ib[3] * 32 + c8);
    f16x8 uc = *reinterpret_cast<const f16x8*>(tab + (size_t)ib[4] * 32 + c8);
    f16x8 ud = *reinterpret_cast<const f16x8*>(tab + (size_t)ib[5] * 32 + c8);
    f16x8 ue = *reinterpret_cast<const f16x8*>(tab + (size_t)ib[6] * 32 + c8);
    f16x8 uf = *reinterpret_cast<const f16x8*>(tab + (size_t)ib[7] * 32 + c8);
    f16x8 g0 = (u0 + u1) + (u2 + u3);
    f16x8 g1 = (u4 + u5) + (u6 + u7);
    f16x8 g2 = (u8 + u9) + (ua + ub);
    f16x8 g3 = (uc + ud) + (ue + uf);
    #pragma unroll
    for (int q = 0; q < 8; ++q)
      acc[q] += ((float)g0[q] + (float)g1[q]) + ((float)g2[q] + (float)g3[q]);
  }
  if (k < e) {
    u16x8 ia = *reinterpret_cast<const u16x8*>(csr_src + k);
    f16x8 u0 = *reinterpret_cast<const f16x8*>(tab + (size_t)ia[0] * 32 + c8);
    f16x8 u1 = *reinterpret_cast<const f16x8*>(tab + (size_t)ia[1] * 32 + c8);
    f16x8 u2 = *reinterpret_cast<const f16x8*>(tab + (size_t)ia[2] * 32 + c8);
    f16x8 u3 = *reinterpret_cast<const f16x8*>(tab + (size_t)ia[3] * 32 + c8);
    f16x8 u4 = *reinterpret_cast<const f16x8*>(tab + (size_t)ia[4] * 32 + c8);
    f16x8 u5 = *reinterpret_cast<const f16x8*>(tab + (size_t)ia[5] * 32 + c8);
    f16x8 u6 = *reinterpret_cast<const f16x8*>(tab + (size_t)ia[6] * 32 + c8);
    f16x8 u7 = *reinterpret_cast<const f16x8*>(tab + (size_t)ia[7] * 32 + c8);
    f16x8 g0 = (u0 + u1) + (u2 + u3);
    f16x8 g1 = (u4 + u5) + (u6 + u7);
    #pragma unroll
    for (int q = 0; q < 8; ++q) acc[q] += (float)g0[q] + (float)g1[q];
  }
  f16x8 o;
  #pragma unroll
  for (int q = 0; q < 8; ++q) o[q] = (f16)acc[q];
  *reinterpret_cast<f16x8*>(dst + (size_t)node * 32 + c8) = o;
}

// ========== LDS staging from blocked [4][SN][32] layout ==========
__device__ __forceinline__ void stage_blocked(
    const f16* __restrict__ src, f16* __restrict__ As,
    int row0, int N, int SN, int t) {
  #pragma unroll
  for (int i = 0; i < 4; ++i) {
    int u = i * 256 + t;          // 1024 chunks of 16B
    int row = u >> 4;
    int sl = (u >> 2) & 3;
    int ck = u & 3;
    int r = row0 + row;
    f16x8 v{};
    if (r < N) v = *reinterpret_cast<const f16x8*>(
        src + ((size_t)sl * SN + r) * 32 + ck * 8);
    *reinterpret_cast<f16x8*>(&As[row * 136 + sl * 32 + ck * 8]) = v;
  }
}

__device__ __forceinline__ void mfma_tile(
    const f16* As, const f16* Ws, int wr, int wc, int ln15, int quad,
    f32x4 (&acc)[2][4]) {
  #pragma unroll
  for (int s = 0; s < 4; ++s) {
    f16x8 a0 = *reinterpret_cast<const f16x8*>(
        &As[(wr * 32 + ln15) * 136 + s * 32 + quad * 8]);
    f16x8 a1 = *reinterpret_cast<const f16x8*>(
        &As[(wr * 32 + 16 + ln15) * 136 + s * 32 + quad * 8]);
    #pragma unroll
    for (int ni = 0; ni < 4; ++ni) {
      f16x8 bf = *reinterpret_cast<const f16x8*>(
          &Ws[(wc * 64 + ni * 16 + ln15) * 136 + s * 32 + quad * 8]);
      acc[0][ni] = __builtin_amdgcn_mfma_f32_16x16x32_f16(a0, bf, acc[0][ni], 0, 0, 0);
      acc[1][ni] = __builtin_amdgcn_mfma_f32_16x16x32_f16(a1, bf, acc[1][ni], 0, 0, 0);
    }
  }
}

// ============ fused gate GEMM (z, r, h-partial in one pass) ========
__global__ __launch_bounds__(256, 3) void gemm3_kernel(
    const f16* __restrict__ A, const f16* __restrict__ Bh,
    const f16* __restrict__ WT, const float* __restrict__ b,
    const f16* __restrict__ hbl, f16* __restrict__ zb,
    f16* __restrict__ cb, float* __restrict__ hpre, int N, int N1, int hSN) {
  __shared__ f16 As[64 * 136];
  __shared__ f16 Ws[128 * 136];
  const int t = threadIdx.x;
  const int w = t >> 6, wr = w >> 1, wc = w & 1;
  const int lane = t & 63, ln15 = lane & 15, quad = lane >> 4;
  const int row0 = blockIdx.x * 64;
  f32x4 accZ[2][4], accR[2][4], accH[2][4];
  #pragma unroll
  for (int i = 0; i < 2; ++i)
    #pragma unroll
    for (int j = 0; j < 4; ++j) {
      accZ[i][j] = (f32x4){0.f, 0.f, 0.f, 0.f};
      accR[i][j] = (f32x4){0.f, 0.f, 0.f, 0.f};
      accH[i][j] = (f32x4){0.f, 0.f, 0.f, 0.f};
    }

  stage_blocked(A, As, row0, N, N1, t);
  #pragma unroll
  for (int g = 0; g < 3; ++g) {          // gates 0,2,4 vs x-aggregate
    const f16* __restrict__ wp = WT + (size_t)(g * 2) * HDIM * HDIM;
    __syncthreads();
    #pragma unroll
    for (int i = 0; i < 8; ++i) {
      int flat = i * 256 + t;
      int n = flat >> 4;
      int o = (flat & 15) * 8;
      *reinterpret_cast<f16x8*>(&Ws[n * 136 + o]) =
          *reinterpret_cast<const f16x8*>(wp + (size_t)n * HDIM + o);
    }
    __syncthreads();
    if (g == 0) mfma_tile(As, Ws, wr, wc, ln15, quad, accZ);
    else if (g == 1) mfma_tile(As, Ws, wr, wc, ln15, quad, accR);
    else mfma_tile(As, Ws, wr, wc, ln15, quad, accH);
  }
  __syncthreads();
  stage_blocked(Bh, As, row0, N, N1, t);
  #pragma unroll
  for (int g = 0; g < 2; ++g) {          // gates 1,3 vs h-aggregate
    const f16* __restrict__ wp = WT + (size_t)(g * 2 + 1) * HDIM * HDIM;
    __syncthreads();
    #pragma unroll
    for (int i = 0; i < 8; ++i) {
      int flat = i * 256 + t;
      int n = flat >> 4;
      int o = (flat & 15) * 8;
      *reinterpret_cast<f16x8*>(&Ws[n * 136 + o]) =
          *reinterpret_cast<const f16x8*>(wp + (size_t)n * HDIM + o);
    }
    __syncthreads();
    if (g == 0) mfma_tile(As, Ws, wr, wc, ln15, quad, accZ);
    else mfma_tile(As, Ws, wr, wc, ln15, quad, accR);
  }

  // ---- epilogue: zpre (linear), c=sigmoid(r)*h (blocked), hpre (f32) ----
  #pragma unroll
  for (int ni = 0; ni < 4; ++ni) {
    const int col = wc * 64 + ni * 16 + ln15;
    const int slc = col >> 5;
    const int cw = col & 31;
    float bz = b[0 * HDIM + col] + b[1 * HDIM + col];
    float br = b[2 * HDIM + col] + b[3 * HDIM + col];
    float bh = b[4 * HDIM + col];
    #pragma unroll
    for (int mi = 0; mi < 2; ++mi) {
      #pragma unroll
      for (int r = 0; r < 4; ++r) {
        int row = row0 + wr * 32 + mi * 16 + quad * 4 + r;
        if (row >= N) continue;
        size_t idx = (size_t)row * HDIM + col;
        zb[idx] = (f16)(accZ[mi][ni][r] + bz);
        float rv = accR[mi][ni][r] + br;
        float rg = 1.f / (1.f + expf(-rv));
        float hv = (float)hbl[((size_t)slc * hSN + row) * 32 + cw];
        cb[((size_t)slc * N1 + row) * 32 + cw] = (f16)(rg * hv);
        hpre[idx] = accH[mi][ni][r] + bh;
      }
    }
  }
}

// ============ final GEMM + GRU combine =======================
__global__ __launch_bounds__(256, 3) void gemm_final_kernel(
    const f16* __restrict__ Ctot, const f16* __restrict__ WT5,
    const float* __restrict__ b5, const f16* __restrict__ zb,
    const f16* __restrict__ hbl, float* __restrict__ outi,
    f16* __restrict__ xb, int N, int N1, int hSN) {
  __shared__ f16 As[64 * 136];
  __shared__ f16 Ws[128 * 136];
  const int t = threadIdx.x;
  const int w = t >> 6, wr = w >> 1, wc = w & 1;
  const int lane = t & 63, ln15 = lane & 15, quad = lane >> 4;
  const int row0 = blockIdx.x * 64;
  f32x4 acc[2][4];
  #pragma unroll
  for (int i = 0; i < 2; ++i)
    #pragma unroll
    for (int j = 0; j < 4; ++j) acc[i][j] = (f32x4){0.f, 0.f, 0.f, 0.f};

  stage_blocked(Ctot, As, row0, N, N1, t);
  #pragma unroll
  for (int i = 0; i < 8; ++i) {
    int flat = i * 256 + t;
    int n = flat >> 4;
    int o = (flat & 15) * 8;
    *reinterpret_cast<f16x8*>(&Ws[n * 136 + o]) =
        *reinterpret_cast<const f16x8*>(WT5 + (size_t)n * HDIM + o);
  }
  __syncthreads();
  mfma_tile(As, Ws, wr, wc, ln15, quad, acc);

  #pragma unroll
  for (int ni = 0; ni < 4; ++ni) {
    const int col = wc * 64 + ni * 16 + ln15;
    const int slc = col >> 5;
    const int cw = col & 31;
    float bias = b5[col];
    #pragma unroll
    for (int mi = 0; mi < 2; ++mi) {
      #pragma unroll
      for (int r = 0; r < 4; ++r) {
        int row = row0 + wr * 32 + mi * 16 + quad * 4 + r;
        if (row >= N) continue;
        size_t idx = (size_t)row * HDIM + col;
        float v = acc[mi][ni][r] + bias + outi[idx];  // + hpre (f32 in outi)
        float ht = tanhf(v);
        float z = 1.f / (1.f + expf(-(float)zb[idx]));
        float hv = (float)hbl[((size_t)slc * hSN + row) * 32 + cw];
        float o = z * hv + (1.f - z) * ht;
        outi[idx] = o;
        xb[((size_t)slc * N1 + row) * 32 + cw] = (f16)o;
      }
    }
  }
}

extern "C" void kernel_launch(void* const* d_in, const int* in_sizes, int n_in,
                              void* d_out, int out_size, void* d_ws, size_t ws_size,
                              hipStream_t stream) {
  const float* inp = (const float*)d_in[0];
  const int*   edg = (const int*)d_in[1];
  const float* h   = (const float*)d_in[2];
  const float* W   = (const float*)d_in[3];
  const float* b   = (const float*)d_in[4];
  float* out = (float*)d_out;

  const int NH = in_sizes[0];      // N*H
  const int N  = NH / HDIM;
  const int E  = in_sizes[1] / 2;
  const int L  = in_sizes[2] / NH;
  const int N1 = N + 1;            // table row stride (zero row at N)
  const size_t NT = (size_t)128 * N1;   // f16 per 4-slice table

  f16* Af   = (f16*)d_ws;               // x-agg / c-agg (blocked, reused)
  f16* Bhf  = Af + NT;                  // h-agg (blocked)
  f16* cbuf = Bhf + NT;                 // sigmoid(r)*h (blocked gather table)
  f16* xbuf = cbuf + NT;                // x f16 (blocked gather table)
  f16* hbuf = xbuf + NT;                // h f16 both layers (blocked, padded)
  f16* zbuf = hbuf + (size_t)L * NT;    // zpre (linear)
  f16* WT   = zbuf + (size_t)NH;        // L*6*H*H transposed f16 weights
  int* deg     = (int*)(WT + (size_t)L * 6 * HDIM * HDIM);
  int* degt    = deg + N;               // true degrees
  int* offs    = degt + N;              // N+1
  int* bsum    = offs + (N + 1);        // 256
  int* boff    = bsum + 256;            // 256
  uintptr_t rp = (uintptr_t)(boff + 256);
  rp = (rp + 63) & ~(uintptr_t)63;      // 64B-align for vector csr loads
  u16* rank    = (u16*)rp;              // E
  u16* csr_src = rank + (size_t)E;      // E + 8N (padded)
  // bucket counters: N*16 ints, live only during CSR build -> overlay on Af
  int* cnt     = (int*)Af;

  const int eblocks = (E + 255) / 256;
  const int fblocks = (E + 1023) / 1024;
  const int nsblocks = (N + 255) / 256;
  const int rowblocks = (N + 63) / 64;
  const int p2blocks = ((N + 63) / 64) * 8;
  const int p1blocks = ((N + 63) / 64) * 4;
  const int cvblocks = (N + 31) / 32;
  const int chunk = (N + 255) / 256;    // <=256 requires N<=65536
  const int hSN = L * N1;

  // ---- one-time per call: CSR build (padded), transpose, f16 tables ----
  hipMemsetAsync(cnt, 0, (size_t)N * 16 * sizeof(int), stream);
  hipLaunchKernelGGL(degrank_kernel, dim3(eblocks), dim3(256), 0, stream,
                     edg, cnt, rank, E);
  hipLaunchKernelGGL(nodescan_kernel, dim3(nsblocks), dim3(256), 0, stream,
                     cnt, deg, degt, N);
  hipLaunchKernelGGL(scan_part_kernel, dim3(256), dim3(256), 0, stream,
                     deg, bsum, N, chunk);
  hipLaunchKernelGGL(scan_top_kernel, dim3(1), dim3(256), 0, stream,
                     bsum, boff, offs, N);
  hipLaunchKernelGGL(scan_fin_kernel, dim3(256), dim3(256), 0, stream,
                     deg, boff, offs, N, chunk);
  hipLaunchKernelGGL(fill_kernel, dim3(fblocks), dim3(256), 0, stream,
                     edg, offs, cnt, rank, csr_src, E);
  hipLaunchKernelGGL(pad_kernel, dim3(nsblocks), dim3(256), 0, stream,
                     offs, degt, deg, csr_src, N);
  hipLaunchKernelGGL(transw_kernel, dim3(16, L * 6), dim3(256), 0, stream,
                     W, WT);
  hipLaunchKernelGGL(convb_kernel, dim3(cvblocks), dim3(256), 0, stream,
                     inp, xbuf, N, N1, 0);
  for (int i = 0; i < L; ++i)
    hipLaunchKernelGGL(convb_kernel, dim3(cvblocks), dim3(256), 0, stream,
                       h + (size_t)i * NH, hbuf, N, hSN, i * N1);
  hipLaunchKernelGGL(zpad_kernel, dim3(1), dim3(256), 0, stream,
                     xbuf, cbuf, hbuf, N, L);

  for (int i = 0; i < L; ++i) {
    const f16* hbl = hbuf + (size_t)i * N1 * 32;  // layer-i base (blocked)
    const f16* WTi = WT + (size_t)i * 6 * HDIM * HDIM;
    const float* bi = b + (size_t)i * 6 * HDIM;
    float* outi = out + (size_t)i * NH;

    hipLaunchKernelGGL(pull2_kernel, dim3(p2blocks), dim3(256), 0, stream,
                       csr_src, offs, xbuf, hbl, Af, Bhf, N, N1, hSN);
    hipLaunchKernelGGL(gemm3_kernel, dim3(rowblocks), dim3(256), 0, stream,
                       Af, Bhf, WTi, bi, hbl, zbuf, cbuf, outi, N, N1, hSN);
    hipLaunchKernelGGL(pull1_kernel, dim3(p1blocks), dim3(256), 0, stream,
                       csr_src, offs, cbuf, Af, N, N1);  // Af = c-agg
    hipLaunchKernelGGL(gemm_final_kernel, dim3(rowblocks), dim3(256), 0, stream,
                       Af, WTi + (size_t)5 * HDIM * HDIM, bi + 5 * HDIM,
                       zbuf, hbl, outi, xbuf, N, N1, hSN);
  }
}

// Round 10
// 591.665 us; speedup vs baseline: 1.5475x; 1.1277x over previous
//
#include <hip/hip_runtime.h>
#include <math.h>
#include <stdint.h>

#define HDIM 128

typedef _Float16 f16;
typedef unsigned short u16;
typedef __attribute__((ext_vector_type(8))) unsigned short u16x8;
typedef __attribute__((ext_vector_type(4))) _Float16 f16x4;
typedef __attribute__((ext_vector_type(8))) _Float16 f16x8;
typedef __attribute__((ext_vector_type(4))) float f32x4;

// ================= CSR build =================
__global__ __launch_bounds__(256) void degrank_kernel(
    const int* __restrict__ edg, int* __restrict__ cnt,
    u16* __restrict__ rank, int E) {
  int e = blockIdx.x * 256 + threadIdx.x;
  if (e < E) {
    int src = edg[e];
    int dst = edg[E + e];
    rank[e] = (u16)atomicAdd(&cnt[dst * 16 + (src >> 12)], 1);
  }
}

// exclusive-scan 16 bucket counters; emit true degree and 8-padded degree
__global__ __launch_bounds__(256) void nodescan_kernel(
    int* __restrict__ cnt, int* __restrict__ deg, int* __restrict__ degt,
    int N) {
  int node = blockIdx.x * 256 + threadIdx.x;
  if (node >= N) return;
  int* c = cnt + node * 16;
  int s = 0;
  #pragma unroll
  for (int b = 0; b < 16; ++b) {
    int v = c[b];
    c[b] = s;
    s += v;
  }
  degt[node] = s;
  deg[node] = (s + 7) & ~7;     // pad to multiple of 8
}

__global__ __launch_bounds__(256) void scan_part_kernel(
    const int* __restrict__ deg, int* __restrict__ bsum, int n, int chunk) {
  __shared__ int red[256];
  const int b = blockIdx.x, t = threadIdx.x;
  const int begin = b * chunk;
  const int end = min(begin + chunk, n);
  int s = 0;
  for (int i = begin + t; i < end; i += 256) s += deg[i];
  red[t] = s;
  __syncthreads();
  for (int off = 128; off > 0; off >>= 1) {
    if (t < off) red[t] += red[t + off];
    __syncthreads();
  }
  if (t == 0) bsum[b] = red[0];
}

__global__ __launch_bounds__(256) void scan_top_kernel(
    const int* __restrict__ bsum, int* __restrict__ boff,
    int* __restrict__ offs, int n) {
  __shared__ int sh[256];
  const int t = threadIdx.x;
  int v = bsum[t];
  sh[t] = v;
  __syncthreads();
  for (int off = 1; off < 256; off <<= 1) {
    int add = (t >= off) ? sh[t - off] : 0;
    __syncthreads();
    sh[t] += add;
    __syncthreads();
  }
  boff[t] = sh[t] - v;
  if (t == 255) offs[n] = sh[255];
}

__global__ __launch_bounds__(256) void scan_fin_kernel(
    const int* __restrict__ deg, const int* __restrict__ boff,
    int* __restrict__ offs, int n, int chunk) {
  __shared__ int sh[256];
  const int b = blockIdx.x, t = threadIdx.x;
  const int idx = b * chunk + t;
  int v = (t < chunk && idx < n) ? deg[idx] : 0;
  sh[t] = v;
  __syncthreads();
  for (int off = 1; off < 256; off <<= 1) {
    int add = (t >= off) ? sh[t - off] : 0;
    __syncthreads();
    sh[t] += add;
    __syncthreads();
  }
  if (t < chunk && idx < n) offs[idx] = boff[b] + sh[t] - v;
}

__global__ __launch_bounds__(256) void fill_kernel(
    const int* __restrict__ edg, const int* __restrict__ offs,
    const int* __restrict__ cnt, const u16* __restrict__ rank,
    u16* __restrict__ csr_src, int E) {
  int i = blockIdx.x * 256 + threadIdx.x;
  int e0 = i * 4;
  if (e0 >= E) return;
  if (e0 + 4 <= E) {
    int4 s4 = *reinterpret_cast<const int4*>(edg + e0);
    int4 d4 = *reinterpret_cast<const int4*>(edg + E + e0);
    ushort4 r4 = *reinterpret_cast<const ushort4*>(rank + e0);
    csr_src[offs[d4.x] + cnt[d4.x * 16 + (s4.x >> 12)] + r4.x] = (u16)s4.x;
    csr_src[offs[d4.y] + cnt[d4.y * 16 + (s4.y >> 12)] + r4.y] = (u16)s4.y;
    csr_src[offs[d4.z] + cnt[d4.z * 16 + (s4.z >> 12)] + r4.z] = (u16)s4.z;
    csr_src[offs[d4.w] + cnt[d4.w * 16 + (s4.w >> 12)] + r4.w] = (u16)s4.w;
  } else {
    for (int e = e0; e < E; ++e) {
      int src = edg[e];
      int dst = edg[E + e];
      csr_src[offs[dst] + cnt[dst * 16 + (src >> 12)] + rank[e]] = (u16)src;
    }
  }
}

// pad slots [offs+degt, offs+deg) -> zero-row index N; also zero the pad
// rows (row N per slice) of x, P and per-layer h tables (threads >= N).
__global__ __launch_bounds__(256) void pad_kernel(
    const int* __restrict__ offs, const int* __restrict__ degt,
    const int* __restrict__ deg, u16* __restrict__ csr,
    f16* __restrict__ xb, f16* __restrict__ Pb, f16* __restrict__ hb,
    int N, int L) {
  int n = blockIdx.x * 256 + threadIdx.x;
  if (n < N) {
    int base = offs[n];
    int a = degt[n], b = deg[n];
    for (int k = base + a; k < base + b; ++k) csr[k] = (u16)N;
  } else {
    int t2 = n - N;
    int rows = 2 + L;
    int total = 4 * rows * 4;
    if (t2 < total) {
      int chunk = t2 & 3;
      int r = (t2 >> 2) % rows;
      int sl = (t2 >> 2) / rows;
      size_t SN1 = (size_t)(N + 1);
      f16* p;
      if (r == 0)      p = xb + (sl * SN1 + N) * 32;
      else if (r == 1) p = Pb + (sl * SN1 + N) * 32;
      else {
        int i = r - 2;
        p = hb + ((size_t)sl * L * SN1 + (size_t)i * SN1 + N) * 32;
      }
      f16x8 z{};
      *reinterpret_cast<f16x8*>(p + chunk * 8) = z;
    }
  }
}

// ===== fp32 [n][128] -> blocked fp16 [4][SN][32]; y=0: x table, y>0: h layer
__global__ __launch_bounds__(256) void convb_kernel(
    const float* __restrict__ inp, const float* __restrict__ h,
    f16* __restrict__ xb, f16* __restrict__ hb, int n, int N1, int NH,
    int L) {
  const int ly = blockIdx.y;
  const float* __restrict__ src = (ly == 0) ? inp : h + (size_t)(ly - 1) * NH;
  f16* __restrict__ dstb = (ly == 0) ? xb : hb;
  const int SN = (ly == 0) ? N1 : L * N1;
  const int rowoff = (ly == 0) ? 0 : (ly - 1) * N1;
  const int t = threadIdx.x;
  const int nloc = t >> 3;
  const int sub = t & 7;
  const int sl = sub >> 1;
  const int hf = sub & 1;
  const int node = blockIdx.x * 32 + nloc;
  if (node >= n) return;
  const float* sp = src + (size_t)node * HDIM + sub * 16;
  f16* dp = dstb + ((size_t)sl * SN + rowoff + node) * 32 + hf * 16;
  float4 v0 = *reinterpret_cast<const float4*>(sp + 0);
  float4 v1 = *reinterpret_cast<const float4*>(sp + 4);
  float4 v2 = *reinterpret_cast<const float4*>(sp + 8);
  float4 v3 = *reinterpret_cast<const float4*>(sp + 12);
  f16x8 o0, o1;
  o0[0]=(f16)v0.x; o0[1]=(f16)v0.y; o0[2]=(f16)v0.z; o0[3]=(f16)v0.w;
  o0[4]=(f16)v1.x; o0[5]=(f16)v1.y; o0[6]=(f16)v1.z; o0[7]=(f16)v1.w;
  o1[0]=(f16)v2.x; o1[1]=(f16)v2.y; o1[2]=(f16)v2.z; o1[3]=(f16)v2.w;
  o1[4]=(f16)v3.x; o1[5]=(f16)v3.y; o1[6]=(f16)v3.z; o1[7]=(f16)v3.w;
  *reinterpret_cast<f16x8*>(dp) = o0;
  *reinterpret_cast<f16x8*>(dp + 8) = o1;
}

// ================= W transpose + fp16: WT[gate][n][k] =================
__global__ __launch_bounds__(256) void transw_kernel(
    const float* __restrict__ W, f16* __restrict__ WT) {
  __shared__ float sh[32][33];
  const int g = blockIdx.y;
  const int ti = blockIdx.x >> 2;
  const int tj = blockIdx.x & 3;
  const float* __restrict__ wp = W + (size_t)g * HDIM * HDIM;
  f16* __restrict__ op = WT + (size_t)g * HDIM * HDIM;
  const int t = threadIdx.x;
  #pragma unroll
  for (int it = 0; it < 4; ++it) {
    int elem = it * 256 + t;
    int r = elem >> 5, c = elem & 31;
    sh[r][c] = wp[(size_t)(ti * 32 + r) * HDIM + tj * 32 + c];
  }
  __syncthreads();
  #pragma unroll
  for (int it = 0; it < 4; ++it) {
    int elem = it * 256 + t;
    int cc = elem >> 5, rr = elem & 31;
    op[(size_t)(tj * 32 + cc) * HDIM + ti * 32 + rr] = (f16)sh[rr][cc];
  }
}

// ================= XCD-sliced pull aggregation (x and h) ==============
__global__ __launch_bounds__(256) void pull2_kernel(
    const u16* __restrict__ csr_src, const int* __restrict__ offs,
    const f16* __restrict__ xb, const f16* __restrict__ hbl,
    f16* __restrict__ A, f16* __restrict__ Bh, int N, int N1, int hSN) {
  const int cls = blockIdx.x & 7;
  const int tid = cls >> 2;            // 0 = x-table, 1 = h-table
  const int sl = cls & 3;
  const int node = (blockIdx.x >> 3) * 64 + (threadIdx.x >> 2);
  if (node >= N) return;
  const int c8 = (threadIdx.x & 3) << 3;
  const f16* __restrict__ tab =
      tid ? hbl + (size_t)sl * hSN * 32 : xb + (size_t)sl * (size_t)N1 * 32;
  f16* __restrict__ dst = (tid ? Bh : A) + (size_t)sl * (size_t)N1 * 32;
  const int s = offs[node];
  const int e = offs[node + 1];
  float acc[8];
  f16x8 sv = *reinterpret_cast<const f16x8*>(tab + (size_t)node * 32 + c8);
  #pragma unroll
  for (int q = 0; q < 8; ++q) acc[q] = (float)sv[q];
  int k = s;
  for (; k + 16 <= e; k += 16) {
    u16x8 ia = *reinterpret_cast<const u16x8*>(csr_src + k);
    u16x8 ib = *reinterpret_cast<const u16x8*>(csr_src + k + 8);
    f16x8 u0 = *reinterpret_cast<const f16x8*>(tab + (size_t)ia[0] * 32 + c8);
    f16x8 u1 = *reinterpret_cast<const f16x8*>(tab + (size_t)ia[1] * 32 + c8);
    f16x8 u2 = *reinterpret_cast<const f16x8*>(tab + (size_t)ia[2] * 32 + c8);
    f16x8 u3 = *reinterpret_cast<const f16x8*>(tab + (size_t)ia[3] * 32 + c8);
    f16x8 u4 = *reinterpret_cast<const f16x8*>(tab + (size_t)ia[4] * 32 + c8);
    f16x8 u5 = *reinterpret_cast<const f16x8*>(tab + (size_t)ia[5] * 32 + c8);
    f16x8 u6 = *reinterpret_cast<const f16x8*>(tab + (size_t)ia[6] * 32 + c8);
    f16x8 u7 = *reinterpret_cast<const f16x8*>(tab + (size_t)ia[7] * 32 + c8);
    f16x8 u8 = *reinterpret_cast<const f16x8*>(tab + (size_t)ib[0] * 32 + c8);
    f16x8 u9 = *reinterpret_cast<const f16x8*>(tab + (size_t)ib[1] * 32 + c8);
    f16x8 ua = *reinterpret_cast<const f16x8*>(tab + (size_t)ib[2] * 32 + c8);
    f16x8 ub = *reinterpret_cast<const f16x8*>(tab + (size_t)ib[3] * 32 + c8);
    f16x8 uc = *reinterpret_cast<const f16x8*>(tab + (size_t)ib[4] * 32 + c8);
    f16x8 ud = *reinterpret_cast<const f16x8*>(tab + (size_t)ib[5] * 32 + c8);
    f16x8 ue = *reinterpret_cast<const f16x8*>(tab + (size_t)ib[6] * 32 + c8);
    f16x8 uf = *reinterpret_cast<const f16x8*>(tab + (size_t)ib[7] * 32 + c8);
    f16x8 g0 = (u0 + u1) + (u2 + u3);   // f16 pair-tree (v_pk_add_f16)
    f16x8 g1 = (u4 + u5) + (u6 + u7);
    f16x8 g2 = (u8 + u9) + (ua + ub);
    f16x8 g3 = (uc + ud) + (ue + uf);
    #pragma unroll
    for (int q = 0; q < 8; ++q)
      acc[q] += ((float)g0[q] + (float)g1[q]) + ((float)g2[q] + (float)g3[q]);
  }
  if (k < e) {                           // exactly 8 remain (padded)
    u16x8 ia = *reinterpret_cast<const u16x8*>(csr_src + k);
    f16x8 u0 = *reinterpret_cast<const f16x8*>(tab + (size_t)ia[0] * 32 + c8);
    f16x8 u1 = *reinterpret_cast<const f16x8*>(tab + (size_t)ia[1] * 32 + c8);
    f16x8 u2 = *reinterpret_cast<const f16x8*>(tab + (size_t)ia[2] * 32 + c8);
    f16x8 u3 = *reinterpret_cast<const f16x8*>(tab + (size_t)ia[3] * 32 + c8);
    f16x8 u4 = *reinterpret_cast<const f16x8*>(tab + (size_t)ia[4] * 32 + c8);
    f16x8 u5 = *reinterpret_cast<const f16x8*>(tab + (size_t)ia[5] * 32 + c8);
    f16x8 u6 = *reinterpret_cast<const f16x8*>(tab + (size_t)ia[6] * 32 + c8);
    f16x8 u7 = *reinterpret_cast<const f16x8*>(tab + (size_t)ia[7] * 32 + c8);
    f16x8 g0 = (u0 + u1) + (u2 + u3);
    f16x8 g1 = (u4 + u5) + (u6 + u7);
    #pragma unroll
    for (int q = 0; q < 8; ++q) acc[q] += (float)g0[q] + (float)g1[q];
  }
  f16x8 o;
  #pragma unroll
  for (int q = 0; q < 8; ++q) o[q] = (f16)acc[q];
  *reinterpret_cast<f16x8*>(dst + (size_t)node * 32 + c8) = o;
}

// ========== LDS staging from blocked [4][SN][32] layout ==========
__device__ __forceinline__ void stage_blocked(
    const f16* __restrict__ src, f16* __restrict__ As,
    int row0, int N, int SN, int t) {
  #pragma unroll
  for (int i = 0; i < 4; ++i) {
    int u = i * 256 + t;          // 1024 chunks of 16B
    int row = u >> 4;
    int sl = (u >> 2) & 3;
    int ck = u & 3;
    int r = row0 + row;
    f16x8 v{};
    if (r < N) v = *reinterpret_cast<const f16x8*>(
        src + ((size_t)sl * SN + r) * 32 + ck * 8);
    *reinterpret_cast<f16x8*>(&As[row * 136 + sl * 32 + ck * 8]) = v;
  }
}

__device__ __forceinline__ void mfma_tile(
    const f16* As, const f16* Ws, int wr, int wc, int ln15, int quad,
    f32x4 (&acc)[2][4]) {
  #pragma unroll
  for (int s = 0; s < 4; ++s) {
    f16x8 a0 = *reinterpret_cast<const f16x8*>(
        &As[(wr * 32 + ln15) * 136 + s * 32 + quad * 8]);
    f16x8 a1 = *reinterpret_cast<const f16x8*>(
        &As[(wr * 32 + 16 + ln15) * 136 + s * 32 + quad * 8]);
    #pragma unroll
    for (int ni = 0; ni < 4; ++ni) {
      f16x8 bf = *reinterpret_cast<const f16x8*>(
          &Ws[(wc * 64 + ni * 16 + ln15) * 136 + s * 32 + quad * 8]);
      acc[0][ni] = __builtin_amdgcn_mfma_f32_16x16x32_f16(a0, bf, acc[0][ni], 0, 0, 0);
      acc[1][ni] = __builtin_amdgcn_mfma_f32_16x16x32_f16(a1, bf, acc[1][ni], 0, 0, 0);
    }
  }
}

// ===== fused gate GEMM: z, r, h-partial AND P = (sigmoid(r)*h) @ W5 =====
// Linearity: agg(cb)@W5 == agg(cb@W5), so projecting cb through W5 here
// lets the final kernel be a pure gather+combine (no GEMM, no staging).
__global__ __launch_bounds__(256, 3) void gemm3_kernel(
    const f16* __restrict__ A, const f16* __restrict__ Bh,
    const f16* __restrict__ WT, const float* __restrict__ b,
    const f16* __restrict__ hbl, f16* __restrict__ zb,
    f16* __restrict__ P, float* __restrict__ hpre, int N, int N1, int hSN) {
  __shared__ f16 As[64 * 136];
  __shared__ f16 Ws[128 * 136];
  const int t = threadIdx.x;
  const int w = t >> 6, wr = w >> 1, wc = w & 1;
  const int lane = t & 63, ln15 = lane & 15, quad = lane >> 4;
  const int row0 = blockIdx.x * 64;
  f32x4 accZ[2][4], accR[2][4], accH[2][4];
  #pragma unroll
  for (int i = 0; i < 2; ++i)
    #pragma unroll
    for (int j = 0; j < 4; ++j) {
      accZ[i][j] = (f32x4){0.f, 0.f, 0.f, 0.f};
      accR[i][j] = (f32x4){0.f, 0.f, 0.f, 0.f};
      accH[i][j] = (f32x4){0.f, 0.f, 0.f, 0.f};
    }

  stage_blocked(A, As, row0, N, N1, t);
  #pragma unroll
  for (int g = 0; g < 3; ++g) {          // gates 0,2,4 vs x-aggregate
    const f16* __restrict__ wp = WT + (size_t)(g * 2) * HDIM * HDIM;
    __syncthreads();
    #pragma unroll
    for (int i = 0; i < 8; ++i) {
      int flat = i * 256 + t;
      int n = flat >> 4;
      int o = (flat & 15) * 8;
      *reinterpret_cast<f16x8*>(&Ws[n * 136 + o]) =
          *reinterpret_cast<const f16x8*>(wp + (size_t)n * HDIM + o);
    }
    __syncthreads();
    if (g == 0) mfma_tile(As, Ws, wr, wc, ln15, quad, accZ);
    else if (g == 1) mfma_tile(As, Ws, wr, wc, ln15, quad, accR);
    else mfma_tile(As, Ws, wr, wc, ln15, quad, accH);
  }
  __syncthreads();
  stage_blocked(Bh, As, row0, N, N1, t);
  #pragma unroll
  for (int g = 0; g < 2; ++g) {          // gates 1,3 vs h-aggregate
    const f16* __restrict__ wp = WT + (size_t)(g * 2 + 1) * HDIM * HDIM;
    __syncthreads();
    #pragma unroll
    for (int i = 0; i < 8; ++i) {
      int flat = i * 256 + t;
      int n = flat >> 4;
      int o = (flat & 15) * 8;
      *reinterpret_cast<f16x8*>(&Ws[n * 136 + o]) =
          *reinterpret_cast<const f16x8*>(wp + (size_t)n * HDIM + o);
    }
    __syncthreads();
    if (g == 0) mfma_tile(As, Ws, wr, wc, ln15, quad, accZ);
    else mfma_tile(As, Ws, wr, wc, ln15, quad, accR);
  }
  __syncthreads();   // all mfma done reading As & Ws

  // stage W5 while epilogue-1 runs
  {
    const f16* __restrict__ wp = WT + (size_t)5 * HDIM * HDIM;
    #pragma unroll
    for (int i = 0; i < 8; ++i) {
      int flat = i * 256 + t;
      int n = flat >> 4;
      int o = (flat & 15) * 8;
      *reinterpret_cast<f16x8*>(&Ws[n * 136 + o]) =
          *reinterpret_cast<const f16x8*>(wp + (size_t)n * HDIM + o);
    }
  }
  // epilogue-1: zb, hpre(f32 into outi, bias b4+b5), cb -> As (for P GEMM)
  #pragma unroll
  for (int ni = 0; ni < 4; ++ni) {
    const int col = wc * 64 + ni * 16 + ln15;
    const int slc = col >> 5;
    const int cw = col & 31;
    float bz = b[0 * HDIM + col] + b[1 * HDIM + col];
    float br = b[2 * HDIM + col] + b[3 * HDIM + col];
    float bh = b[4 * HDIM + col] + b[5 * HDIM + col];
    #pragma unroll
    for (int mi = 0; mi < 2; ++mi) {
      #pragma unroll
      for (int r = 0; r < 4; ++r) {
        int rowl = wr * 32 + mi * 16 + quad * 4 + r;
        int row = row0 + rowl;
        float rv = accR[mi][ni][r] + br;
        float rg = 1.f / (1.f + expf(-rv));
        float hv = 0.f;
        if (row < N) {
          size_t idx = (size_t)row * HDIM + col;
          zb[idx] = (f16)(accZ[mi][ni][r] + bz);
          hpre[idx] = accH[mi][ni][r] + bh;
          hv = (float)hbl[((size_t)slc * hSN + row) * 32 + cw];
        }
        As[rowl * 136 + col] = (f16)(rg * hv);
      }
    }
  }
  __syncthreads();
  f32x4 accP[2][4];
  #pragma unroll
  for (int i = 0; i < 2; ++i)
    #pragma unroll
    for (int j = 0; j < 4; ++j) accP[i][j] = (f32x4){0.f, 0.f, 0.f, 0.f};
  mfma_tile(As, Ws, wr, wc, ln15, quad, accP);

  // epilogue-2: P (blocked gather table)
  #pragma unroll
  for (int ni = 0; ni < 4; ++ni) {
    const int col = wc * 64 + ni * 16 + ln15;
    const int slc = col >> 5;
    const int cw = col & 31;
    #pragma unroll
    for (int mi = 0; mi < 2; ++mi) {
      #pragma unroll
      for (int r = 0; r < 4; ++r) {
        int row = row0 + wr * 32 + mi * 16 + quad * 4 + r;
        if (row >= N) continue;
        P[((size_t)slc * N1 + row) * 32 + cw] = (f16)accP[mi][ni][r];
      }
    }
  }
}

// ===== final: gather P (XCD-sliced) + GRU combine; no GEMM needed =====
__global__ __launch_bounds__(256) void gru_final_kernel(
    const u16* __restrict__ csr_src, const int* __restrict__ offs,
    const f16* __restrict__ P, const f16* __restrict__ zb,
    const f16* __restrict__ hbl, float* __restrict__ outi,
    f16* __restrict__ xb, int N, int N1, int hSN) {
  const int sl = blockIdx.x & 3;
  const int node = (blockIdx.x >> 2) * 64 + (threadIdx.x >> 2);
  if (node >= N) return;
  const int c8 = (threadIdx.x & 3) << 3;
  const f16* __restrict__ tab = P + (size_t)sl * (size_t)N1 * 32;
  const int s = offs[node];
  const int e = offs[node + 1];
  float acc[8];
  f16x8 sv = *reinterpret_cast<const f16x8*>(tab + (size_t)node * 32 + c8);
  #pragma unroll
  for (int q = 0; q < 8; ++q) acc[q] = (float)sv[q];
  int k = s;
  for (; k + 16 <= e; k += 16) {
    u16x8 ia = *reinterpret_cast<const u16x8*>(csr_src + k);
    u16x8 ib = *reinterpret_cast<const u16x8*>(csr_src + k + 8);
    f16x8 u0 = *reinterpret_cast<const f16x8*>(tab + (size_t)ia[0] * 32 + c8);
    f16x8 u1 = *reinterpret_cast<const f16x8*>(tab + (size_t)ia[1] * 32 + c8);
    f16x8 u2 = *reinterpret_cast<const f16x8*>(tab + (size_t)ia[2] * 32 + c8);
    f16x8 u3 = *reinterpret_cast<const f16x8*>(tab + (size_t)ia[3] * 32 + c8);
    f16x8 u4 = *reinterpret_cast<const f16x8*>(tab + (size_t)ia[4] * 32 + c8);
    f16x8 u5 = *reinterpret_cast<const f16x8*>(tab + (size_t)ia[5] * 32 + c8);
    f16x8 u6 = *reinterpret_cast<const f16x8*>(tab + (size_t)ia[6] * 32 + c8);
    f16x8 u7 = *reinterpret_cast<const f16x8*>(tab + (size_t)ia[7] * 32 + c8);
    f16x8 u8 = *reinterpret_cast<const f16x8*>(tab + (size_t)ib[0] * 32 + c8);
    f16x8 u9 = *reinterpret_cast<const f16x8*>(tab + (size_t)ib[1] * 32 + c8);
    f16x8 ua = *reinterpret_cast<const f16x8*>(tab + (size_t)ib[2] * 32 + c8);
    f16x8 ub = *reinterpret_cast<const f16x8*>(tab + (size_t)ib[3] * 32 + c8);
    f16x8 uc = *reinterpret_cast<const f16x8*>(tab + (size_t)ib[4] * 32 + c8);
    f16x8 ud = *reinterpret_cast<const f16x8*>(tab + (size_t)ib[5] * 32 + c8);
    f16x8 ue = *reinterpret_cast<const f16x8*>(tab + (size_t)ib[6] * 32 + c8);
    f16x8 uf = *reinterpret_cast<const f16x8*>(tab + (size_t)ib[7] * 32 + c8);
    f16x8 g0 = (u0 + u1) + (u2 + u3);
    f16x8 g1 = (u4 + u5) + (u6 + u7);
    f16x8 g2 = (u8 + u9) + (ua + ub);
    f16x8 g3 = (uc + ud) + (ue + uf);
    #pragma unroll
    for (int q = 0; q < 8; ++q)
      acc[q] += ((float)g0[q] + (float)g1[q]) + ((float)g2[q] + (float)g3[q]);
  }
  if (k < e) {
    u16x8 ia = *reinterpret_cast<const u16x8*>(csr_src + k);
    f16x8 u0 = *reinterpret_cast<const f16x8*>(tab + (size_t)ia[0] * 32 + c8);
    f16x8 u1 = *reinterpret_cast<const f16x8*>(tab + (size_t)ia[1] * 32 + c8);
    f16x8 u2 = *reinterpret_cast<const f16x8*>(tab + (size_t)ia[2] * 32 + c8);
    f16x8 u3 = *reinterpret_cast<const f16x8*>(tab + (size_t)ia[3] * 32 + c8);
    f16x8 u4 = *reinterpret_cast<const f16x8*>(tab + (size_t)ia[4] * 32 + c8);
    f16x8 u5 = *reinterpret_cast<const f16x8*>(tab + (size_t)ia[5] * 32 + c8);
    f16x8 u6 = *reinterpret_cast<const f16x8*>(tab + (size_t)ia[6] * 32 + c8);
    f16x8 u7 = *reinterpret_cast<const f16x8*>(tab + (size_t)ia[7] * 32 + c8);
    f16x8 g0 = (u0 + u1) + (u2 + u3);
    f16x8 g1 = (u4 + u5) + (u6 + u7);
    #pragma unroll
    for (int q = 0; q < 8; ++q) acc[q] += (float)g0[q] + (float)g1[q];
  }
  // GRU combine: out = z*h + (1-z)*tanh(hpre + agg(P))
  const size_t idx = (size_t)node * HDIM + sl * 32 + c8;
  float4 hp0 = *reinterpret_cast<const float4*>(outi + idx);
  float4 hp1 = *reinterpret_cast<const float4*>(outi + idx + 4);
  f16x8 zv = *reinterpret_cast<const f16x8*>(zb + idx);
  f16x8 hv = *reinterpret_cast<const f16x8*>(
      hbl + ((size_t)sl * hSN + node) * 32 + c8);
  float4 o0, o1;
  f16x8 xo;
  #pragma unroll
  for (int q = 0; q < 8; ++q) {
    float hp = (q < 4) ? (&hp0.x)[q] : (&hp1.x)[q - 4];
    float ht = tanhf(hp + acc[q]);
    float z = 1.f / (1.f + expf(-(float)zv[q]));
    float o = z * (float)hv[q] + (1.f - z) * ht;
    if (q < 4) (&o0.x)[q] = o; else (&o1.x)[q - 4] = o;
    xo[q] = (f16)o;
  }
  *reinterpret_cast<float4*>(outi + idx) = o0;
  *reinterpret_cast<float4*>(outi + idx + 4) = o1;
  *reinterpret_cast<f16x8*>(xb + ((size_t)sl * N1 + node) * 32 + c8) = xo;
}

extern "C" void kernel_launch(void* const* d_in, const int* in_sizes, int n_in,
                              void* d_out, int out_size, void* d_ws, size_t ws_size,
                              hipStream_t stream) {
  const float* inp = (const float*)d_in[0];
  const int*   edg = (const int*)d_in[1];
  const float* h   = (const float*)d_in[2];
  const float* W   = (const float*)d_in[3];
  const float* b   = (const float*)d_in[4];
  float* out = (float*)d_out;

  const int NH = in_sizes[0];      // N*H
  const int N  = NH / HDIM;
  const int E  = in_sizes[1] / 2;
  const int L  = in_sizes[2] / NH;
  const int N1 = N + 1;            // table row stride (zero row at N)
  const size_t NT = (size_t)128 * N1;   // f16 per 4-slice table

  f16* Af   = (f16*)d_ws;               // x-agg (blocked)
  f16* Bhf  = Af + NT;                  // h-agg (blocked)
  f16* Pbuf = Bhf + NT;                 // P = cb@W5 (blocked gather table)
  f16* xbuf = Pbuf + NT;                // x f16 (blocked gather table)
  f16* hbuf = xbuf + NT;                // h f16 both layers (blocked, padded)
  f16* zbuf = hbuf + (size_t)L * NT;    // zpre (linear)
  f16* WT   = zbuf + (size_t)NH;        // L*6*H*H transposed f16 weights
  int* deg     = (int*)(WT + (size_t)L * 6 * HDIM * HDIM);
  int* degt    = deg + N;               // true degrees
  int* offs    = degt + N;              // N+1
  int* bsum    = offs + (N + 1);        // 256
  int* boff    = bsum + 256;            // 256
  uintptr_t rp = (uintptr_t)(boff + 256);
  rp = (rp + 63) & ~(uintptr_t)63;      // 64B-align for vector csr loads
  u16* rank    = (u16*)rp;              // E
  u16* csr_src = rank + (size_t)E;      // E + 8N (padded)
  // bucket counters: N*16 ints, live only during CSR build -> overlay on Af
  int* cnt     = (int*)Af;

  const int eblocks = (E + 255) / 256;
  const int fblocks = (E + 1023) / 1024;
  const int nsblocks = (N + 255) / 256;
  const int pdblocks = (N + 256 + 255) / 256;   // pad + zero-row threads
  const int rowblocks = (N + 63) / 64;
  const int p2blocks = ((N + 63) / 64) * 8;
  const int p1blocks = ((N + 63) / 64) * 4;
  const int cvblocks = (N + 31) / 32;
  const int chunk = (N + 255) / 256;    // <=256 requires N<=65536
  const int hSN = L * N1;

  // ---- one-time per call: CSR build (padded), transpose, f16 tables ----
  hipMemsetAsync(cnt, 0, (size_t)N * 16 * sizeof(int), stream);
  hipLaunchKernelGGL(degrank_kernel, dim3(eblocks), dim3(256), 0, stream,
                     edg, cnt, rank, E);
  hipLaunchKernelGGL(nodescan_kernel, dim3(nsblocks), dim3(256), 0, stream,
                     cnt, deg, degt, N);
  hipLaunchKernelGGL(scan_part_kernel, dim3(256), dim3(256), 0, stream,
                     deg, bsum, N, chunk);
  hipLaunchKernelGGL(scan_top_kernel, dim3(1), dim3(256), 0, stream,
                     bsum, boff, offs, N);
  hipLaunchKernelGGL(scan_fin_kernel, dim3(256), dim3(256), 0, stream,
                     deg, boff, offs, N, chunk);
  hipLaunchKernelGGL(fill_kernel, dim3(fblocks), dim3(256), 0, stream,
                     edg, offs, cnt, rank, csr_src, E);
  hipLaunchKernelGGL(pad_kernel, dim3(pdblocks), dim3(256), 0, stream,
                     offs, degt, deg, csr_src, xbuf, Pbuf, hbuf, N, L);
  hipLaunchKernelGGL(transw_kernel, dim3(16, L * 6), dim3(256), 0, stream,
                     W, WT);
  hipLaunchKernelGGL(convb_kernel, dim3(cvblocks, L + 1), dim3(256), 0, stream,
                     inp, h, xbuf, hbuf, N, N1, NH, L);

  for (int i = 0; i < L; ++i) {
    const f16* hbl = hbuf + (size_t)i * N1 * 32;  // layer-i base (blocked)
    const f16* WTi = WT + (size_t)i * 6 * HDIM * HDIM;
    const float* bi = b + (size_t)i * 6 * HDIM;
    float* outi = out + (size_t)i * NH;

    hipLaunchKernelGGL(pull2_kernel, dim3(p2blocks), dim3(256), 0, stream,
                       csr_src, offs, xbuf, hbl, Af, Bhf, N, N1, hSN);
    hipLaunchKernelGGL(gemm3_kernel, dim3(rowblocks), dim3(256), 0, stream,
                       Af, Bhf, WTi, bi, hbl, zbuf, Pbuf, outi, N, N1, hSN);
    hipLaunchKernelGGL(gru_final_kernel, dim3(p1blocks), dim3(256), 0, stream,
                       csr_src, offs, Pbuf, zbuf, hbl, outi, xbuf, N, N1, hSN);
  }
}